// Round 3
// baseline (969.203 us; speedup 1.0000x reference)
//
#include <hip/hip_runtime.h>
#include <math.h>

#define RR 25
#define HH 8
#define EE 1024
#define NCN 27

typedef short bf16x8 __attribute__((ext_vector_type(8)));
typedef float f32x4 __attribute__((ext_vector_type(4)));
typedef unsigned short us4 __attribute__((ext_vector_type(4)));
typedef unsigned short us8 __attribute__((ext_vector_type(8)));

__device__ __forceinline__ unsigned short f2bf(float x) {
    union { float f; unsigned int u; } v; v.f = x;
    const unsigned int u = v.u;
    return (unsigned short)((u + 0x7fffu + ((u >> 16) & 1u)) >> 16);
}
__device__ __forceinline__ float bf2f(unsigned short h) {
    union { unsigned int u; float f; } v; v.u = ((unsigned int)h) << 16;
    return v.f;
}

// ---------------- block reduce (256 threads, wave=64) ----------------
__device__ __forceinline__ float block_reduce_sum_256(float v, float* red) {
#pragma unroll
    for (int off = 32; off > 0; off >>= 1) v += __shfl_down(v, off, 64);
    const int lane = threadIdx.x & 63, wid = threadIdx.x >> 6;
    if (lane == 0) red[wid] = v;
    __syncthreads();
    if (threadIdx.x == 0) red[0] = red[0] + red[1] + red[2] + red[3];
    __syncthreads();
    const float r = red[0];
    __syncthreads();
    return r;
}

// ---------------- emb layernorm (row of 1024) + pre-split planes ----------------
__global__ __launch_bounds__(256) void k_ln_emb(
    const float* __restrict__ emb, const float* __restrict__ g,
    const float* __restrict__ b, float* __restrict__ out,
    unsigned short* __restrict__ eh, unsigned short* __restrict__ el)
{
    __shared__ float red[4];
    const int t = blockIdx.x;
    const float* row = emb + (size_t)t * EE;
    float4 x = reinterpret_cast<const float4*>(row)[threadIdx.x];
    float s = x.x + x.y + x.z + x.w;
    s = block_reduce_sum_256(s, red);
    const float m = s * (1.0f / 1024.0f);
    const float d0 = x.x - m, d1 = x.y - m, d2 = x.z - m, d3 = x.w - m;
    float sq = d0*d0 + d1*d1 + d2*d2 + d3*d3;
    sq = block_reduce_sum_256(sq, red);
    const float rs = rsqrtf(sq * (1.0f / 1024.0f) + 1e-16f);
    const float4 gv = reinterpret_cast<const float4*>(g)[threadIdx.x];
    const float4 bv = reinterpret_cast<const float4*>(b)[threadIdx.x];
    float o[4];
    o[0] = d0 * rs * gv.x + bv.x;
    o[1] = d1 * rs * gv.y + bv.y;
    o[2] = d2 * rs * gv.z + bv.z;
    o[3] = d3 * rs * gv.w + bv.w;
    float4 of; of.x = o[0]; of.y = o[1]; of.z = o[2]; of.w = o[3];
    reinterpret_cast<float4*>(out + (size_t)t * EE)[threadIdx.x] = of;
    us4 hv, lv;
#pragma unroll
    for (int j = 0; j < 4; ++j) {
        const unsigned short h = f2bf(o[j]);
        hv[j] = h; lv[j] = f2bf(o[j] - bf2f(h));
    }
    *reinterpret_cast<us4*>(eh + (size_t)t * EE + threadIdx.x * 4) = hv;
    *reinterpret_cast<us4*>(el + (size_t)t * EE + threadIdx.x * 4) = lv;
}

// ---------------- split all 4 W tensors into bf16 hi/lo planes ----------------
// grid (8192, 4); per tensor: h-plane [8M shorts] then l-plane [8M shorts]
#define WTEN 16777216   // shorts per tensor block (2 planes x 8M)
#define WPLN 8388608    // shorts per plane
__global__ __launch_bounds__(256) void k_splitw(
    const float* __restrict__ w0, const float* __restrict__ w1,
    const float* __restrict__ w2, const float* __restrict__ w3,
    unsigned short* __restrict__ wsp)
{
    const int t = blockIdx.y;
    const float* src = (t == 0) ? w0 : ((t == 1) ? w1 : ((t == 2) ? w2 : w3));
    unsigned short* hb = wsp + (size_t)t * WTEN;
    unsigned short* lb = hb + WPLN;
    const size_t q = (size_t)blockIdx.x * 256 + threadIdx.x;
    const float4 x = reinterpret_cast<const float4*>(src)[q];
    const float xf[4] = {x.x, x.y, x.z, x.w};
    us4 hv, lv;
#pragma unroll
    for (int j = 0; j < 4; ++j) {
        const unsigned short h = f2bf(xf[j]);
        hv[j] = h; lv[j] = f2bf(xf[j] - bf2f(h));
    }
    *reinterpret_cast<us4*>(hb + q * 4) = hv;
    *reinterpret_cast<us4*>(lb + q * 4) = lv;
}

// =====================================================================
// Split-bf16 MFMA GEMM: C[64t x 64f] = sum_e A[t,e]*B[f,e]
// 256 thr = 4 waves, each a 32x32 quadrant (2x2 of 16x16x32 MFMA).
// C += Ah*Bh + Ah*Bl + Al*Bh  (rel err ~1e-5).
// LDS rows padded to 40 shorts -> even bank distribution.
// =====================================================================
struct SplitTiles {
    unsigned short Ah[64][40], Al[64][40], Bh[64][40], Bl[64][40];
};

#define MFMA_COMPUTE(SM)                                                         \
    {                                                                            \
        bf16x8 ah_[2], al_[2], bh_[2], bl_[2];                                   \
        _Pragma("unroll")                                                        \
        for (int m = 0; m < 2; ++m) {                                            \
            const int r = wr * 32 + m * 16 + fr;                                 \
            ah_[m] = *reinterpret_cast<const bf16x8*>(&(SM).Ah[r][ch * 8]);      \
            al_[m] = *reinterpret_cast<const bf16x8*>(&(SM).Al[r][ch * 8]);      \
        }                                                                        \
        _Pragma("unroll")                                                        \
        for (int n = 0; n < 2; ++n) {                                            \
            const int r = wc * 32 + n * 16 + fr;                                 \
            bh_[n] = *reinterpret_cast<const bf16x8*>(&(SM).Bh[r][ch * 8]);      \
            bl_[n] = *reinterpret_cast<const bf16x8*>(&(SM).Bl[r][ch * 8]);      \
        }                                                                        \
        _Pragma("unroll")                                                        \
        for (int m = 0; m < 2; ++m)                                              \
            _Pragma("unroll")                                                    \
            for (int n = 0; n < 2; ++n) {                                        \
                acc[m][n] = __builtin_amdgcn_mfma_f32_16x16x32_bf16(ah_[m], bh_[n], acc[m][n], 0, 0, 0); \
                acc[m][n] = __builtin_amdgcn_mfma_f32_16x16x32_bf16(ah_[m], bl_[n], acc[m][n], 0, 0, 0); \
                acc[m][n] = __builtin_amdgcn_mfma_f32_16x16x32_bf16(al_[m], bh_[n], acc[m][n], 0, 0, 0); \
            }                                                                    \
    }

// on-the-fly split staging (f32 sources) — used by k_qk_mfma and fallback proj
#define MFMA_STAGE_SPLIT(ABASE, BBASE, SM)                                       \
    {                                                                            \
        float4 ra[2], rb[2];                                                     \
        _Pragma("unroll")                                                        \
        for (int l = 0; l < 2; ++l) {                                            \
            const int id = l * 256 + tid;                                        \
            const int row = id >> 3, c4 = (id & 7) * 4;                          \
            ra[l] = *reinterpret_cast<const float4*>((ABASE) + (size_t)row * EE + k0 + c4); \
            rb[l] = *reinterpret_cast<const float4*>((BBASE) + (size_t)row * EE + k0 + c4); \
        }                                                                        \
        __syncthreads();                                                         \
        _Pragma("unroll")                                                        \
        for (int l = 0; l < 2; ++l) {                                            \
            const int id = l * 256 + tid;                                        \
            const int row = id >> 3, c4 = (id & 7) * 4;                          \
            const float xa[4] = {ra[l].x, ra[l].y, ra[l].z, ra[l].w};            \
            const float xb[4] = {rb[l].x, rb[l].y, rb[l].z, rb[l].w};            \
            us4 ahv, alv, bhv, blv;                                              \
            _Pragma("unroll")                                                    \
            for (int j = 0; j < 4; ++j) {                                        \
                const unsigned short ha = f2bf(xa[j]);                           \
                ahv[j] = ha; alv[j] = f2bf(xa[j] - bf2f(ha));                    \
                const unsigned short hb = f2bf(xb[j]);                           \
                bhv[j] = hb; blv[j] = f2bf(xb[j] - bf2f(hb));                    \
            }                                                                    \
            *reinterpret_cast<us4*>(&(SM).Ah[row][c4]) = ahv;                    \
            *reinterpret_cast<us4*>(&(SM).Al[row][c4]) = alv;                    \
            *reinterpret_cast<us4*>(&(SM).Bh[row][c4]) = bhv;                    \
            *reinterpret_cast<us4*>(&(SM).Bl[row][c4]) = blv;                    \
        }                                                                        \
        __syncthreads();                                                         \
    }

// ---------------- Q/K projection from pre-split planes (fast path) ----------------
// grid: (16 f-tiles, 25 t-tiles, 2*8); z: h = z>>1, pk = z&1
__global__ __launch_bounds__(256) void k_proj_pre(
    const unsigned short* __restrict__ eh, const unsigned short* __restrict__ el,
    const unsigned short* __restrict__ wq, const unsigned short* __restrict__ wk,
    float* __restrict__ Qb, float* __restrict__ Kb, int qkHeadStride)
{
    __shared__ __align__(16) SplitTiles sm;
    const int h = blockIdx.z >> 1;
    const int pk = blockIdx.z & 1;
    const unsigned short* base = pk ? wk : wq;
    const unsigned short* Wh = base + (size_t)h * 1048576;
    const unsigned short* Wl = base + WPLN + (size_t)h * 1048576;
    float* C = (pk ? Kb : Qb) + (size_t)h * qkHeadStride;
    const int bx = blockIdx.x, by = blockIdx.y;
    const int tid = threadIdx.x;
    const int lane = tid & 63, w = tid >> 6;
    const int wr = w >> 1, wc = w & 1;
    const int fr = lane & 15, ch = lane >> 4;
    const int srow = tid >> 2, c8 = (tid & 3) * 8;   // staging role
    const unsigned short* Ah_src = eh + ((size_t)(by * 64 + srow)) * EE + c8;
    const unsigned short* Al_src = el + ((size_t)(by * 64 + srow)) * EE + c8;
    const unsigned short* Bh_src = Wh + ((size_t)(bx * 64 + srow)) * EE + c8;
    const unsigned short* Bl_src = Wl + ((size_t)(bx * 64 + srow)) * EE + c8;
    f32x4 acc[2][2] = {};
    for (int k0 = 0; k0 < EE; k0 += 32) {
        const us8 va = *reinterpret_cast<const us8*>(Ah_src + k0);
        const us8 vb = *reinterpret_cast<const us8*>(Al_src + k0);
        const us8 vc = *reinterpret_cast<const us8*>(Bh_src + k0);
        const us8 vd = *reinterpret_cast<const us8*>(Bl_src + k0);
        __syncthreads();
        *reinterpret_cast<us8*>(&sm.Ah[srow][c8]) = va;
        *reinterpret_cast<us8*>(&sm.Al[srow][c8]) = vb;
        *reinterpret_cast<us8*>(&sm.Bh[srow][c8]) = vc;
        *reinterpret_cast<us8*>(&sm.Bl[srow][c8]) = vd;
        __syncthreads();
        MFMA_COMPUTE(sm)
    }
    const int rg = lane >> 4;
#pragma unroll
    for (int m = 0; m < 2; ++m)
#pragma unroll
        for (int n = 0; n < 2; ++n)
#pragma unroll
            for (int q = 0; q < 4; ++q) {
                const int row = by * 64 + wr * 32 + m * 16 + rg * 4 + q;
                const int col = bx * 64 + wc * 32 + n * 16 + fr;
                C[(size_t)row * EE + col] = acc[m][n][q];
            }
}

// ---------------- Q/K projection, on-the-fly split (fallback path) ----------------
__global__ __launch_bounds__(256) void k_proj_mfma(
    const float* __restrict__ A,
    const float* __restrict__ WQ, const float* __restrict__ WK,
    float* __restrict__ Qb, float* __restrict__ Kb, int qkHeadStride)
{
    __shared__ __align__(16) SplitTiles sm;
    const int h = blockIdx.z >> 1;
    const int pk = blockIdx.z & 1;
    const float* W = (pk ? WK : WQ) + (size_t)h * EE * EE;
    float* C = (pk ? Kb : Qb) + (size_t)h * qkHeadStride;
    const int bx = blockIdx.x, by = blockIdx.y;
    const int tid = threadIdx.x;
    const int lane = tid & 63, w = tid >> 6;
    const int wr = w >> 1, wc = w & 1;
    const int fr = lane & 15, ch = lane >> 4;
    const float* Abase = A + (size_t)by * 64 * EE;
    const float* Bbase = W + (size_t)bx * 64 * EE;
    f32x4 acc[2][2] = {};
    for (int k0 = 0; k0 < EE; k0 += 32) {
        MFMA_STAGE_SPLIT(Abase, Bbase, sm)
        MFMA_COMPUTE(sm)
    }
    const int rg = lane >> 4;
#pragma unroll
    for (int m = 0; m < 2; ++m)
#pragma unroll
        for (int n = 0; n < 2; ++n)
#pragma unroll
            for (int q = 0; q < 4; ++q) {
                const int row = by * 64 + wr * 32 + m * 16 + rg * 4 + q;
                const int col = bx * 64 + wc * 32 + n * 16 + fr;
                C[(size_t)row * EE + col] = acc[m][n][q];
            }
}

// ---------------- QK^T (/32) + column softmax, MFMA split-bf16 ----------------
__global__ __launch_bounds__(256) void k_qk_mfma(
    const float* __restrict__ Qall, const float* __restrict__ Kall,
    float* __restrict__ attn_all, int qkHeadStride, int attnHeadStride)
{
    __shared__ __align__(16) union { SplitTiles t; float Ss[64][65]; } u;
    __shared__ float redm[4][64];
    __shared__ float reds[4][64];
    const int r = blockIdx.x;
    const int h = blockIdx.y;
    const float* Q = Qall + (size_t)h * qkHeadStride;
    const float* K = Kall + (size_t)h * qkHeadStride;
    float* attn = attn_all + (size_t)h * attnHeadStride + (size_t)r * 4096;
    const int tid = threadIdx.x;
    const int lane = tid & 63, w = tid >> 6;
    const int wr = w >> 1, wc = w & 1;
    const int fr = lane & 15, ch = lane >> 4;
    const float* Abase = Q + (size_t)r * 64 * EE;
    const float* Bbase = K + (size_t)r * 64 * EE;
    f32x4 acc[2][2] = {};
    for (int k0 = 0; k0 < EE; k0 += 32) {
        MFMA_STAGE_SPLIT(Abase, Bbase, u.t)
        MFMA_COMPUTE(u.t)
    }
    __syncthreads();
    const int rg = lane >> 4;
#pragma unroll
    for (int m = 0; m < 2; ++m)
#pragma unroll
        for (int n = 0; n < 2; ++n)
#pragma unroll
            for (int q = 0; q < 4; ++q)
                u.Ss[wr * 32 + m * 16 + rg * 4 + q][wc * 32 + n * 16 + fr] =
                    acc[m][n][q] * (1.0f / 32.0f);
    __syncthreads();
    const int j = tid & 63, seg = tid >> 6;
    float mx = -1e30f;
#pragma unroll
    for (int i = 0; i < 16; ++i) mx = fmaxf(mx, u.Ss[seg * 16 + i][j]);
    redm[seg][j] = mx;
    __syncthreads();
    const float cm = fmaxf(fmaxf(redm[0][j], redm[1][j]), fmaxf(redm[2][j], redm[3][j]));
    float ssum = 0.f;
#pragma unroll
    for (int i = 0; i < 16; ++i) {
        const float e = __expf(u.Ss[seg * 16 + i][j] - cm);
        u.Ss[seg * 16 + i][j] = e;
        ssum += e;
    }
    reds[seg][j] = ssum;
    __syncthreads();
    const float inv = 1.0f / (reds[0][j] + reds[1][j] + reds[2][j] + reds[3][j]);
#pragma unroll
    for (int i = 0; i < 16; ++i)
        attn[(seg * 16 + i) * 64 + j] = u.Ss[seg * 16 + i][j] * inv;
}

// ---------------- f32 vector GEMM bits (small kernels) ----------------
#define GEMM_INNER()                                                            \
    _Pragma("unroll 8")                                                         \
    for (int kk = 0; kk < 32; ++kk) {                                           \
        const float a0 = As[ty4+0][kk], a1 = As[ty4+1][kk],                     \
                    a2 = As[ty4+2][kk], a3 = As[ty4+3][kk];                     \
        const float b0 = Bs[tx4+0][kk], b1 = Bs[tx4+1][kk],                     \
                    b2 = Bs[tx4+2][kk], b3 = Bs[tx4+3][kk];                     \
        acc[0][0] += a0*b0; acc[0][1] += a0*b1; acc[0][2] += a0*b2; acc[0][3] += a0*b3; \
        acc[1][0] += a1*b0; acc[1][1] += a1*b1; acc[1][2] += a1*b2; acc[1][3] += a1*b3; \
        acc[2][0] += a2*b0; acc[2][1] += a2*b1; acc[2][2] += a2*b2; acc[2][3] += a2*b3; \
        acc[3][0] += a3*b0; acc[3][1] += a3*b1; acc[3][2] += a3*b2; acc[3][3] += a3*b3; \
    }

#define GEMM_LOAD_TILES(ABASE, BBASE)                                           \
    _Pragma("unroll")                                                           \
    for (int l = 0; l < 2; ++l) {                                               \
        const int idx = l * 256 + tid;                                          \
        const int row = idx >> 3, seg = (idx & 7) * 4;                          \
        const float4 va = *reinterpret_cast<const float4*>((ABASE) + (size_t)row * EE + k0 + seg); \
        As[row][seg+0] = va.x; As[row][seg+1] = va.y;                           \
        As[row][seg+2] = va.z; As[row][seg+3] = va.w;                           \
        const float4 vb = *reinterpret_cast<const float4*>((BBASE) + (size_t)row * EE + k0 + seg); \
        Bs[row][seg+0] = vb.x; Bs[row][seg+1] = vb.y;                           \
        Bs[row][seg+2] = vb.z; Bs[row][seg+3] = vb.w;                           \
    }

// ---------------- BR ----------------
__global__ __launch_bounds__(64) void k_br(
    const float* __restrict__ bst, const float* __restrict__ bsi,
    const int* __restrict__ iti, const int* __restrict__ iii,
    const float* __restrict__ attn_t, const float* __restrict__ attn_i,
    float* __restrict__ br_t, float* __restrict__ br_i)
{
    __shared__ float bw[64];
    const int dp = blockIdx.x;
    const int h = blockIdx.y;
    const int j = threadIdx.x;
    const float* attn;
    float* out;
    if (dp < RR) {
        const int d = dp;
        const int rb = iti[d * 64];
        const float* p = bst + ((size_t)(d * 64) * 64 + j) * 4;
        bw[j] = 0.25f * (p[0] + p[1] + p[2] + p[3]);
        attn = attn_t + ((size_t)h * RR + rb) * 4096;
        out = br_t + (size_t)d * 64 * 8;
    } else {
        const int d = dp - RR;
        const int rb = iii[d];
        const float* p = bsi + ((size_t)d * 64 + j) * 4;
        bw[j] = 0.25f * (p[0] + p[1] + p[2] + p[3]);
        attn = attn_i + ((size_t)h * RR + rb) * 4096;
        out = br_i + (size_t)d * 64 * 8;
    }
    __syncthreads();
    float acc = 0.f;
#pragma unroll 8
    for (int i = 0; i < 64; ++i) acc += bw[i] * attn[i * 64 + j];
    out[(size_t)j * 8 + h] = acc;
}

// ---------------- norms ----------------
__global__ __launch_bounds__(256) void k_norms(
    const float* __restrict__ br_t, const float* __restrict__ br_i,
    float* __restrict__ na, float* __restrict__ nb)
{
    const int t = blockIdx.x * 256 + threadIdx.x;
    if (t < 1600) {
        float s = 0.f;
#pragma unroll
        for (int h = 0; h < 8; ++h) { const float v = br_t[(size_t)t*8 + h]; s += v*v; }
        na[t] = fmaxf(sqrtf(s), 1e-15f);
    } else if (t < 1600 + 4096) {
        const int u = t - 1600;
        float s = 0.f;
#pragma unroll
        for (int h = 0; h < 8; ++h) { const float v = br_i[(size_t)u*8 + h]; s += v*v; }
        nb[u] = fmaxf(sqrtf(s), 1e-15f);
    }
}

// ---------------- BS raw ----------------
__global__ __launch_bounds__(256) void k_bs(
    const float* __restrict__ br_t, const float* __restrict__ br_i,
    const float* __restrict__ na, const float* __restrict__ nb,
    float* __restrict__ raw)
{
    const int p = blockIdx.x;
#pragma unroll
    for (int it = 0; it < 16; ++it) {
        const int o = it * 256 + threadIdx.x;
        const int q = o >> 6, j = o & 63;
        const float* a = br_t + ((size_t)p * 64 + j) * 8;
        const float* b = br_i + ((size_t)q * 64 + j) * 8;
        float dot = 0.f;
#pragma unroll
        for (int h = 0; h < 8; ++h) dot += a[h] * b[h];
        raw[(size_t)p * 4096 + o] = dot / (na[p * 64 + j] * nb[q * 64 + j]);
    }
}

// ---------------- log-softmax rows of 27 ----------------
__global__ __launch_bounds__(256) void k_lsm(
    const float* __restrict__ cst, const float* __restrict__ csi,
    float* __restrict__ lt, float* __restrict__ li)
{
    const int row = blockIdx.x * 256 + threadIdx.x;
    if (row >= 1600 + 4096) return;
    const float* src;
    float* dst;
    if (row < 1600) {
        const int d = row >> 6, i = row & 63;
        src = cst + ((size_t)(d * 64) * 64 + i) * NCN * 4;
        dst = lt + (size_t)row * NCN;
    } else {
        const int u = row - 1600;
        const int q = u >> 6, i = u & 63;
        src = csi + ((size_t)q * 64 + i) * NCN * 4;
        dst = li + (size_t)u * NCN;
    }
    float x[NCN];
    float m = -1e30f;
#pragma unroll
    for (int k = 0; k < NCN; ++k) {
        x[k] = 0.25f * (src[k*4] + src[k*4+1] + src[k*4+2] + src[k*4+3]);
        m = fmaxf(m, x[k]);
    }
    float s = 0.f;
#pragma unroll
    for (int k = 0; k < NCN; ++k) s += __expf(x[k] - m);
    const float lse = m + __logf(s);
#pragma unroll
    for (int k = 0; k < NCN; ++k) dst[k] = x[k] - lse;
}

// ---------------- CS raw ----------------
__global__ __launch_bounds__(256) void k_cs(
    const float* __restrict__ lt, const float* __restrict__ li, float* __restrict__ raw)
{
    const int p = blockIdx.x;
    for (int it = 0; it < 16; ++it) {
        const int o = it * 256 + threadIdx.x;
        const int q = o >> 6, i = o & 63;
        const float* a = lt + ((size_t)p * 64 + i) * NCN;
        const float* b = li + ((size_t)q * 64 + i) * NCN;
        float la[NCN], lb[NCN];
        float m = -1e30f;
#pragma unroll
        for (int k = 0; k < NCN; ++k) {
            la[k] = a[k]; lb[k] = b[k];
            m = fmaxf(m, 0.5f * (la[k] + lb[k]));
        }
        float z = 0.f;
#pragma unroll
        for (int k = 0; k < NCN; ++k) z += __expf(0.5f * (la[k] + lb[k]) - m);
        const float lse = m + __logf(z);
        float kt = 0.f, ki = 0.f;
#pragma unroll
        for (int k = 0; k < NCN; ++k) {
            const float M = 0.5f * (la[k] + lb[k]) - lse;
            const float eM = __expf(M);
            kt += eM * (M - la[k]);
            ki += eM * (M - lb[k]);
        }
        raw[(size_t)p * 4096 + o] = -(kt + ki) * (0.5f / 27.0f);
    }
}

// ---------------- ob_emb ----------------
__global__ __launch_bounds__(256) void k_obemb(
    const float* __restrict__ emb, const float* __restrict__ Wos,
    const float* __restrict__ bos, const int* __restrict__ iii,
    const int* __restrict__ cob, float* __restrict__ ob)
{
    __shared__ float As[64][33];
    __shared__ float Bs[64][33];
    __shared__ int gidx[64];
    const int bx = blockIdx.x;
    const int tid = threadIdx.x;
    const int tx = tid & 15, ty = tid >> 4;
    const int ty4 = ty * 4, tx4 = tx * 4;
    if (tid < 64) gidx[tid] = iii[tid] * 64 + cob[tid];
    __syncthreads();
    const float* Bbase = Wos + (size_t)bx * 64 * EE;
    float acc[4][4] = {};
    for (int k0 = 0; k0 < EE; k0 += 32) {
#pragma unroll
        for (int l = 0; l < 2; ++l) {
            const int idx = l * 256 + tid;
            const int row = idx >> 3, seg = (idx & 7) * 4;
            const float4 va = *reinterpret_cast<const float4*>(emb + (size_t)gidx[row] * EE + k0 + seg);
            As[row][seg+0] = va.x; As[row][seg+1] = va.y; As[row][seg+2] = va.z; As[row][seg+3] = va.w;
            const float4 vb = *reinterpret_cast<const float4*>(Bbase + (size_t)row * EE + k0 + seg);
            Bs[row][seg+0] = vb.x; Bs[row][seg+1] = vb.y; Bs[row][seg+2] = vb.z; Bs[row][seg+3] = vb.w;
        }
        __syncthreads();
        GEMM_INNER()
        __syncthreads();
    }
#pragma unroll
    for (int q = 0; q < 4; ++q)
#pragma unroll
        for (int r2 = 0; r2 < 4; ++r2)
            ob[(size_t)(ty4 + q) * EE + bx*64 + tx4 + r2] = acc[q][r2] + bos[bx*64 + tx4 + r2];
}

// ---------------- OS raw ----------------
__global__ __launch_bounds__(256) void k_os(
    const float* __restrict__ ob, const float* __restrict__ emb, float* __restrict__ raw)
{
    __shared__ float As[64][33];
    __shared__ float Bs[64][33];
    const int p = blockIdx.x;
    const int tid = threadIdx.x;
    const int tx = tid & 15, ty = tid >> 4;
    const int ty4 = ty * 4, tx4 = tx * 4;
    const float* Abase = ob;
    const float* Bbase = emb + (size_t)p * 64 * EE;
    float acc[4][4] = {};
    for (int k0 = 0; k0 < EE; k0 += 32) {
        GEMM_LOAD_TILES(Abase, Bbase)
        __syncthreads();
        GEMM_INNER()
        __syncthreads();
    }
#pragma unroll
    for (int q = 0; q < 4; ++q)
#pragma unroll
        for (int r2 = 0; r2 < 4; ++r2)
            raw[(size_t)p * 4096 + (ty4 + q) * 64 + tx4 + r2] = acc[q][r2];
}

// ---------------- final LN ----------------
__global__ __launch_bounds__(256) void k_final_ln(
    const float* __restrict__ raw,
    const float* __restrict__ BSg, const float* __restrict__ BSb,
    const float* __restrict__ CSg, const float* __restrict__ CSb,
    const float* __restrict__ OSg, const float* __restrict__ OSb,
    float* __restrict__ out)
{
    __shared__ float red[4];
    const int s = blockIdx.x, p = blockIdx.y;
    const float* g  = (s == 0) ? BSg : ((s == 1) ? CSg : OSg);
    const float* bb = (s == 0) ? BSb : ((s == 1) ? CSb : OSb);
    const float* x = raw + ((size_t)s * RR + p) * 4096;
    float v[16];
    float sum = 0.f;
#pragma unroll
    for (int it = 0; it < 16; ++it) { v[it] = x[it * 256 + threadIdx.x]; sum += v[it]; }
    sum = block_reduce_sum_256(sum, red);
    const float m = sum * (1.0f / 4096.0f);
    float sq = 0.f;
#pragma unroll
    for (int it = 0; it < 16; ++it) { const float d = v[it] - m; sq += d * d; }
    sq = block_reduce_sum_256(sq, red);
    const float rs = rsqrtf(sq * (1.0f / 4096.0f) + 1e-5f);
    float* o = out + ((size_t)s * RR + p) * 4096;
#pragma unroll
    for (int it = 0; it < 16; ++it) {
        const int oo = it * 256 + threadIdx.x;
        o[oo] = (v[it] - m) * rs * g[oo] + bb[oo];
    }
}

extern "C" void kernel_launch(void* const* d_in, const int* in_sizes, int n_in,
                              void* d_out, int out_size, void* d_ws, size_t ws_size,
                              hipStream_t stream)
{
    const float* bst = (const float*)d_in[0];
    const float* bsi = (const float*)d_in[1];
    const float* cst = (const float*)d_in[2];
    const float* csi = (const float*)d_in[3];
    const int*   iti = (const int*)d_in[4];
    const int*   iii = (const int*)d_in[5];
    const int*   cob = (const int*)d_in[6];
    const float* embw = (const float*)d_in[7];
    const float* eg  = (const float*)d_in[8];
    const float* ebb = (const float*)d_in[9];
    const float* WQt = (const float*)d_in[10];
    const float* WKt = (const float*)d_in[11];
    const float* WQi = (const float*)d_in[12];
    const float* WKi = (const float*)d_in[13];
    const float* Wos = (const float*)d_in[14];
    const float* bos = (const float*)d_in[15];
    const float* BSg = (const float*)d_in[16];
    const float* BSb = (const float*)d_in[17];
    const float* CSg = (const float*)d_in[18];
    const float* CSb = (const float*)d_in[19];
    const float* OSg = (const float*)d_in[20];
    const float* OSb = (const float*)d_in[21];

    // --- tiered workspace (floats) ---
    const size_t tailF  = 819200ull*2 + 12800 + 32768 + 1600 + 4096 + 43200 + 110592 + 65536 + 307200;
    const size_t baseF  = 1638400ull + 819200 + 819200;           // emb_n + planes
    const size_t wspF   = 33554432ull;                            // W split planes
    const size_t qk8F   = 2ull * 8 * 1600 * EE;                   // Q+K, 8 heads, f32
    const size_t qk1F   = 2ull * 1600 * EE;                       // Q+K, 1 head
    const size_t needBig = (baseF + wspF + qk8F + tailF) * 4;     // ~261 MB
    const size_t needMid = (baseF + qk8F + tailF) * 4;            // ~127 MB
    const int tier = (ws_size >= needBig) ? 2 : ((ws_size >= needMid) ? 1 : 0);

    float* ws = (float*)d_ws;
    size_t cur = 0;
    float* emb_n = ws + cur;                      cur += 1638400;
    unsigned short* emb_h = (unsigned short*)(ws + cur); cur += 819200;
    unsigned short* emb_l = (unsigned short*)(ws + cur); cur += 819200;
    unsigned short* wsp = nullptr;
    if (tier == 2) { wsp = (unsigned short*)(ws + cur); cur += wspF; }
    const size_t qkSz = (tier >= 1) ? (size_t)8 * 1600 * EE : (size_t)1600 * EE;
    float* Qbuf   = ws + cur;        cur += qkSz;
    float* Kbuf   = ws + cur;        cur += qkSz;
    float* attn_t = ws + cur;        cur += 819200;
    float* attn_i = ws + cur;        cur += 819200;
    float* br_t   = ws + cur;        cur += 12800;
    float* br_i   = ws + cur;        cur += 32768;
    float* na     = ws + cur;        cur += 1600;
    float* nb     = ws + cur;        cur += 4096;
    float* lt     = ws + cur;        cur += 43200;
    float* li     = ws + cur;        cur += 110592;
    float* ob     = ws + cur;        cur += 65536;
    float* raw    = ws + cur;        cur += 307200;

    k_ln_emb<<<1600, 256, 0, stream>>>(embw, eg, ebb, emb_n, emb_h, emb_l);
    if (tier == 2)
        k_splitw<<<dim3(8192, 4), 256, 0, stream>>>(WQt, WKt, WQi, WKi, wsp);

    for (int w = 0; w < 2; ++w) {
        const float* WQ = w ? WQi : WQt;
        const float* WK = w ? WKi : WKt;
        float* attn = w ? attn_i : attn_t;
        if (tier == 2) {
            k_proj_pre<<<dim3(16, 25, 16), 256, 0, stream>>>(
                emb_h, emb_l, wsp + (size_t)(2*w) * WTEN, wsp + (size_t)(2*w+1) * WTEN,
                Qbuf, Kbuf, 1600 * EE);
            k_qk_mfma<<<dim3(25, 8), 256, 0, stream>>>(Qbuf, Kbuf, attn, 1600 * EE, RR * 4096);
        } else if (tier == 1) {
            k_proj_mfma<<<dim3(16, 25, 16), 256, 0, stream>>>(emb_n, WQ, WK, Qbuf, Kbuf, 1600 * EE);
            k_qk_mfma<<<dim3(25, 8), 256, 0, stream>>>(Qbuf, Kbuf, attn, 1600 * EE, RR * 4096);
        } else {
            for (int h = 0; h < HH; ++h) {
                k_proj_mfma<<<dim3(16, 25, 2), 256, 0, stream>>>(
                    emb_n, WQ + (size_t)h * EE * EE, WK + (size_t)h * EE * EE, Qbuf, Kbuf, 0);
                k_qk_mfma<<<dim3(25, 1), 256, 0, stream>>>(
                    Qbuf, Kbuf, attn + (size_t)h * RR * 4096, 0, 0);
            }
        }
    }

    k_br<<<dim3(RR + 64, 8), 64, 0, stream>>>(bst, bsi, iti, iii, attn_t, attn_i, br_t, br_i);
    k_norms<<<23, 256, 0, stream>>>(br_t, br_i, na, nb);
    k_bs<<<25, 256, 0, stream>>>(br_t, br_i, na, nb, raw);
    k_lsm<<<23, 256, 0, stream>>>(cst, csi, lt, li);
    k_cs<<<25, 256, 0, stream>>>(lt, li, raw + 102400);
    k_obemb<<<16, 256, 0, stream>>>(embw, Wos, bos, iii, cob, ob);
    k_os<<<25, 256, 0, stream>>>(ob, embw, raw + 204800);
    k_final_ln<<<dim3(3, RR), 256, 0, stream>>>(raw, BSg, BSb, CSg, CSb, OSg, OSb, (float*)d_out);
}

// Round 4
// 862.030 us; speedup vs baseline: 1.1243x; 1.1243x over previous
//
#include <hip/hip_runtime.h>
#include <math.h>

#define RR 25
#define HH 8
#define EE 1024
#define NCN 27

typedef short bf16x8 __attribute__((ext_vector_type(8)));
typedef float f32x4 __attribute__((ext_vector_type(4)));
typedef unsigned short us4 __attribute__((ext_vector_type(4)));
typedef unsigned short us8 __attribute__((ext_vector_type(8)));

__device__ __forceinline__ unsigned short f2bf(float x) {
    union { float f; unsigned int u; } v; v.f = x;
    const unsigned int u = v.u;
    return (unsigned short)((u + 0x7fffu + ((u >> 16) & 1u)) >> 16);
}
__device__ __forceinline__ float bf2f(unsigned short h) {
    union { unsigned int u; float f; } v; v.u = ((unsigned int)h) << 16;
    return v.f;
}

// ---------------- block reduce (256 threads, wave=64) ----------------
__device__ __forceinline__ float block_reduce_sum_256(float v, float* red) {
#pragma unroll
    for (int off = 32; off > 0; off >>= 1) v += __shfl_down(v, off, 64);
    const int lane = threadIdx.x & 63, wid = threadIdx.x >> 6;
    if (lane == 0) red[wid] = v;
    __syncthreads();
    if (threadIdx.x == 0) red[0] = red[0] + red[1] + red[2] + red[3];
    __syncthreads();
    const float r = red[0];
    __syncthreads();
    return r;
}

// =====================================================================
// Fragment-frame layout: one 16x16x32 MFMA fragment = 1 frame = 512 shorts.
//   element (row,k): lane = (row&15) + 16*((k>>3)&3), j = k&7
//   A planes  : frame2 = ((ktile*100 + (row>>4))*2 + plane)   [M=1600]
//   W planes  : per head, frame2 = ((ktile*64 + (f>>4))*2 + plane)
// K-major frames => the (ktile) slab needed by a block is CONTIGUOUS.
// =====================================================================
#define WTEN 16777216ull      // shorts per split weight tensor (8 heads x 2 planes x 1M)
#define WHEAD 2097152ull      // shorts per head (2 planes x 1M)

// ---------------- emb layernorm + frag-ordered split planes ----------------
__global__ __launch_bounds__(256) void k_ln_emb(
    const float* __restrict__ emb, const float* __restrict__ g,
    const float* __restrict__ b, float* __restrict__ out,
    unsigned short* __restrict__ Apl)
{
    __shared__ float red[4];
    const int t = blockIdx.x;
    const float* row = emb + (size_t)t * EE;
    float4 x = reinterpret_cast<const float4*>(row)[threadIdx.x];
    float s = x.x + x.y + x.z + x.w;
    s = block_reduce_sum_256(s, red);
    const float m = s * (1.0f / 1024.0f);
    const float d0 = x.x - m, d1 = x.y - m, d2 = x.z - m, d3 = x.w - m;
    float sq = d0*d0 + d1*d1 + d2*d2 + d3*d3;
    sq = block_reduce_sum_256(sq, red);
    const float rs = rsqrtf(sq * (1.0f / 1024.0f) + 1e-16f);
    const float4 gv = reinterpret_cast<const float4*>(g)[threadIdx.x];
    const float4 bv = reinterpret_cast<const float4*>(b)[threadIdx.x];
    float o[4];
    o[0] = d0 * rs * gv.x + bv.x;
    o[1] = d1 * rs * gv.y + bv.y;
    o[2] = d2 * rs * gv.z + bv.z;
    o[3] = d3 * rs * gv.w + bv.w;
    float4 of; of.x = o[0]; of.y = o[1]; of.z = o[2]; of.w = o[3];
    reinterpret_cast<float4*>(out + (size_t)t * EE)[threadIdx.x] = of;
    us4 hv, lv;
#pragma unroll
    for (int j = 0; j < 4; ++j) {
        const unsigned short h = f2bf(o[j]);
        hv[j] = h; lv[j] = f2bf(o[j] - bf2f(h));
    }
    const int k0 = threadIdx.x * 4;
    const int kt = k0 >> 5, kc = (k0 >> 3) & 3, j0 = k0 & 7;
    const int lane = (t & 15) + 16 * kc;
    const size_t base = ((size_t)(kt * 100 + (t >> 4)) * 2) * 512 + lane * 8 + j0;
    *reinterpret_cast<us4*>(Apl + base)       = hv;
    *reinterpret_cast<us4*>(Apl + base + 512) = lv;
}

// ---------------- split 4 weight tensors into frag-ordered planes ----------------
__global__ __launch_bounds__(256) void k_splitw(
    const float* __restrict__ w0, const float* __restrict__ w1,
    const float* __restrict__ w2, const float* __restrict__ w3,
    unsigned short* __restrict__ wsp)
{
    const int t = blockIdx.y;
    const float* src = (t == 0) ? w0 : ((t == 1) ? w1 : ((t == 2) ? w2 : w3));
    unsigned short* dst = wsp + (size_t)t * WTEN;
    const size_t q = (size_t)blockIdx.x * 256 + threadIdx.x;
    const float4 x = reinterpret_cast<const float4*>(src)[q];
    const float xf[4] = {x.x, x.y, x.z, x.w};
    us4 hv, lv;
#pragma unroll
    for (int j = 0; j < 4; ++j) {
        const unsigned short h = f2bf(xf[j]);
        hv[j] = h; lv[j] = f2bf(xf[j] - bf2f(h));
    }
    const size_t e4 = q * 4;
    const int h = (int)(e4 >> 20);
    const int rem = (int)(e4 & 1048575);
    const int f = rem >> 10, e = rem & 1023;
    const int kt = e >> 5, kc = (e >> 3) & 3, j0 = e & 7;
    const int lane = (f & 15) + 16 * kc;
    const size_t base = (size_t)h * WHEAD + ((size_t)(kt * 64 + (f >> 4)) * 2) * 512 + lane * 8 + j0;
    *reinterpret_cast<us4*>(dst + base)       = hv;
    *reinterpret_cast<us4*>(dst + base + 512) = lv;
}

// ---------------- fast projection: 64x256 tile, frag frames, no conflicts ----------------
// per-w launch: grid x = 1600.  fid -> xcd(0..7) -> z = pk*8+h clustered per XCD.
__global__ __launch_bounds__(256) void k_proj2(
    const unsigned short* __restrict__ Apl,
    const unsigned short* __restrict__ Wpl,   // already offset to this w's 2 tensors
    float* __restrict__ Qb, float* __restrict__ Kb)
{
    __shared__ __align__(16) unsigned short As_l[8 * 512];    // 8 KB
    __shared__ __align__(16) unsigned short Bs_l[32 * 512];   // 32 KB
    const int fid = blockIdx.x;
    const int xcd = fid & 7;
    const int iw = fid >> 3;               // 0..199
    const int z = xcd + (iw / 100) * 8;    // 0..15  (pk*8 + h)
    const int mb = iw % 100;
    const int by = mb >> 2, bx = mb & 3;
    const int pk = z >> 3, h = z & 7;
    const unsigned short* Wb = Wpl + (size_t)pk * WTEN + (size_t)h * WHEAD;
    float* C = (pk ? Kb : Qb) + (size_t)h * 1600 * EE;
    const int tid = threadIdx.x;
    const int lane = tid & 63, wv = tid >> 6;
    const int by4 = by * 4, bx16 = bx * 16;
    f32x4 acc[4][4] = {};
    for (int kt = 0; kt < 32; ++kt) {
        const unsigned short* aslab = Apl + ((size_t)(kt * 100 + by4)) * 1024;
        const unsigned short* bslab = Wb  + ((size_t)(kt * 64  + bx16)) * 1024;
        us8 ra0 = *reinterpret_cast<const us8*>(aslab + (size_t)tid * 8);
        us8 ra1 = *reinterpret_cast<const us8*>(aslab + (size_t)(256 + tid) * 8);
        us8 rb[8];
#pragma unroll
        for (int c = 0; c < 8; ++c)
            rb[c] = *reinterpret_cast<const us8*>(bslab + (size_t)(c * 256 + tid) * 8);
        __syncthreads();
        *reinterpret_cast<us8*>(As_l + tid * 8) = ra0;
        *reinterpret_cast<us8*>(As_l + (256 + tid) * 8) = ra1;
#pragma unroll
        for (int c = 0; c < 8; ++c)
            *reinterpret_cast<us8*>(Bs_l + (c * 256 + tid) * 8) = rb[c];
        __syncthreads();
        bf16x8 ah[4], al[4], bh[4], bl[4];
#pragma unroll
        for (int m = 0; m < 4; ++m) {
            ah[m] = *reinterpret_cast<const bf16x8*>(As_l + (m * 2 + 0) * 512 + lane * 8);
            al[m] = *reinterpret_cast<const bf16x8*>(As_l + (m * 2 + 1) * 512 + lane * 8);
        }
#pragma unroll
        for (int n = 0; n < 4; ++n) {
            const int nt = wv * 4 + n;
            bh[n] = *reinterpret_cast<const bf16x8*>(Bs_l + (nt * 2 + 0) * 512 + lane * 8);
            bl[n] = *reinterpret_cast<const bf16x8*>(Bs_l + (nt * 2 + 1) * 512 + lane * 8);
        }
#pragma unroll
        for (int m = 0; m < 4; ++m)
#pragma unroll
            for (int n = 0; n < 4; ++n) {
                acc[m][n] = __builtin_amdgcn_mfma_f32_16x16x32_bf16(ah[m], bh[n], acc[m][n], 0, 0, 0);
                acc[m][n] = __builtin_amdgcn_mfma_f32_16x16x32_bf16(ah[m], bl[n], acc[m][n], 0, 0, 0);
                acc[m][n] = __builtin_amdgcn_mfma_f32_16x16x32_bf16(al[m], bh[n], acc[m][n], 0, 0, 0);
            }
    }
    const int rg = lane >> 4, fr = lane & 15;
#pragma unroll
    for (int m = 0; m < 4; ++m)
#pragma unroll
        for (int n = 0; n < 4; ++n)
#pragma unroll
            for (int q = 0; q < 4; ++q) {
                const int row = by * 64 + m * 16 + rg * 4 + q;
                const int col = bx * 256 + wv * 64 + n * 16 + fr;
                C[(size_t)row * EE + col] = acc[m][n][q];
            }
}

// =====================================================================
// On-the-fly split machinery (64x64 tile, 4 waves as 2x2 quadrants) —
// verified pattern from round 3.  Used by QK, obemb, os, fallback proj.
// =====================================================================
struct SplitTiles {
    unsigned short Ah[64][40], Al[64][40], Bh[64][40], Bl[64][40];
};

#define MFMA_COMPUTE(SM)                                                         \
    {                                                                            \
        bf16x8 ah_[2], al_[2], bh_[2], bl_[2];                                   \
        _Pragma("unroll")                                                        \
        for (int m = 0; m < 2; ++m) {                                            \
            const int r = wr * 32 + m * 16 + fr;                                 \
            ah_[m] = *reinterpret_cast<const bf16x8*>(&(SM).Ah[r][ch * 8]);      \
            al_[m] = *reinterpret_cast<const bf16x8*>(&(SM).Al[r][ch * 8]);      \
        }                                                                        \
        _Pragma("unroll")                                                        \
        for (int n = 0; n < 2; ++n) {                                            \
            const int r = wc * 32 + n * 16 + fr;                                 \
            bh_[n] = *reinterpret_cast<const bf16x8*>(&(SM).Bh[r][ch * 8]);      \
            bl_[n] = *reinterpret_cast<const bf16x8*>(&(SM).Bl[r][ch * 8]);      \
        }                                                                        \
        _Pragma("unroll")                                                        \
        for (int m = 0; m < 2; ++m)                                              \
            _Pragma("unroll")                                                    \
            for (int n = 0; n < 2; ++n) {                                        \
                acc[m][n] = __builtin_amdgcn_mfma_f32_16x16x32_bf16(ah_[m], bh_[n], acc[m][n], 0, 0, 0); \
                acc[m][n] = __builtin_amdgcn_mfma_f32_16x16x32_bf16(ah_[m], bl_[n], acc[m][n], 0, 0, 0); \
                acc[m][n] = __builtin_amdgcn_mfma_f32_16x16x32_bf16(al_[m], bh_[n], acc[m][n], 0, 0, 0); \
            }                                                                    \
    }

// AROW/BROW: expressions mapping local row (0..63) -> const float* row base
#define MFMA_STAGE_SPLIT_GEN(AROW, BROW, SM)                                     \
    {                                                                            \
        float4 ra[2], rb[2];                                                     \
        _Pragma("unroll")                                                        \
        for (int l = 0; l < 2; ++l) {                                            \
            const int id = l * 256 + tid;                                        \
            const int row = id >> 3, c4 = (id & 7) * 4;                          \
            ra[l] = *reinterpret_cast<const float4*>((AROW(row)) + k0 + c4);     \
            rb[l] = *reinterpret_cast<const float4*>((BROW(row)) + k0 + c4);     \
        }                                                                        \
        __syncthreads();                                                         \
        _Pragma("unroll")                                                        \
        for (int l = 0; l < 2; ++l) {                                            \
            const int id = l * 256 + tid;                                        \
            const int row = id >> 3, c4 = (id & 7) * 4;                          \
            const float xa[4] = {ra[l].x, ra[l].y, ra[l].z, ra[l].w};            \
            const float xb[4] = {rb[l].x, rb[l].y, rb[l].z, rb[l].w};            \
            us4 ahv, alv, bhv, blv;                                              \
            _Pragma("unroll")                                                    \
            for (int j = 0; j < 4; ++j) {                                        \
                const unsigned short ha = f2bf(xa[j]);                           \
                ahv[j] = ha; alv[j] = f2bf(xa[j] - bf2f(ha));                    \
                const unsigned short hb = f2bf(xb[j]);                           \
                bhv[j] = hb; blv[j] = f2bf(xb[j] - bf2f(hb));                    \
            }                                                                    \
            *reinterpret_cast<us4*>(&(SM).Ah[row][c4]) = ahv;                    \
            *reinterpret_cast<us4*>(&(SM).Al[row][c4]) = alv;                    \
            *reinterpret_cast<us4*>(&(SM).Bh[row][c4]) = bhv;                    \
            *reinterpret_cast<us4*>(&(SM).Bl[row][c4]) = blv;                    \
        }                                                                        \
        __syncthreads();                                                         \
    }

// ---------------- fallback projection (on-the-fly split, f32 inputs) ----------------
__global__ __launch_bounds__(256) void k_proj_mfma(
    const float* __restrict__ A,
    const float* __restrict__ WQ, const float* __restrict__ WK,
    float* __restrict__ Qb, float* __restrict__ Kb, int qkHeadStride)
{
    __shared__ __align__(16) SplitTiles sm;
    const int h = blockIdx.z >> 1;
    const int pk = blockIdx.z & 1;
    const float* W = (pk ? WK : WQ) + (size_t)h * EE * EE;
    float* C = (pk ? Kb : Qb) + (size_t)h * qkHeadStride;
    const int bx = blockIdx.x, by = blockIdx.y;
    const int tid = threadIdx.x;
    const int lane = tid & 63, w = tid >> 6;
    const int wr = w >> 1, wc = w & 1;
    const int fr = lane & 15, ch = lane >> 4;
    const float* Abase = A + (size_t)by * 64 * EE;
    const float* Bbase = W + (size_t)bx * 64 * EE;
#define AROWP(r) (Abase + (size_t)(r) * EE)
#define BROWP(r) (Bbase + (size_t)(r) * EE)
    f32x4 acc[2][2] = {};
    for (int k0 = 0; k0 < EE; k0 += 32) {
        MFMA_STAGE_SPLIT_GEN(AROWP, BROWP, sm)
        MFMA_COMPUTE(sm)
    }
#undef AROWP
#undef BROWP
    const int rg = lane >> 4;
#pragma unroll
    for (int m = 0; m < 2; ++m)
#pragma unroll
        for (int n = 0; n < 2; ++n)
#pragma unroll
            for (int q = 0; q < 4; ++q) {
                const int row = by * 64 + wr * 32 + m * 16 + rg * 4 + q;
                const int col = bx * 64 + wc * 32 + n * 16 + fr;
                C[(size_t)row * EE + col] = acc[m][n][q];
            }
}

// ---------------- QK^T (/32) + column softmax ----------------
__global__ __launch_bounds__(256) void k_qk_mfma(
    const float* __restrict__ Qall, const float* __restrict__ Kall,
    float* __restrict__ attn_all, int qkHeadStride, int attnHeadStride)
{
    __shared__ __align__(16) union { SplitTiles t; float Ss[64][65]; } u;
    __shared__ float redm[4][64];
    __shared__ float reds[4][64];
    const int r = blockIdx.x;
    const int h = blockIdx.y;
    const float* Q = Qall + (size_t)h * qkHeadStride;
    const float* K = Kall + (size_t)h * qkHeadStride;
    float* attn = attn_all + (size_t)h * attnHeadStride + (size_t)r * 4096;
    const int tid = threadIdx.x;
    const int lane = tid & 63, w = tid >> 6;
    const int wr = w >> 1, wc = w & 1;
    const int fr = lane & 15, ch = lane >> 4;
    const float* Abase = Q + (size_t)r * 64 * EE;
    const float* Bbase = K + (size_t)r * 64 * EE;
#define AROWP(rr) (Abase + (size_t)(rr) * EE)
#define BROWP(rr) (Bbase + (size_t)(rr) * EE)
    f32x4 acc[2][2] = {};
    for (int k0 = 0; k0 < EE; k0 += 32) {
        MFMA_STAGE_SPLIT_GEN(AROWP, BROWP, u.t)
        MFMA_COMPUTE(u.t)
    }
#undef AROWP
#undef BROWP
    __syncthreads();
    const int rg = lane >> 4;
#pragma unroll
    for (int m = 0; m < 2; ++m)
#pragma unroll
        for (int n = 0; n < 2; ++n)
#pragma unroll
            for (int q = 0; q < 4; ++q)
                u.Ss[wr * 32 + m * 16 + rg * 4 + q][wc * 32 + n * 16 + fr] =
                    acc[m][n][q] * (1.0f / 32.0f);
    __syncthreads();
    const int j = tid & 63, seg = tid >> 6;
    float mx = -1e30f;
#pragma unroll
    for (int i = 0; i < 16; ++i) mx = fmaxf(mx, u.Ss[seg * 16 + i][j]);
    redm[seg][j] = mx;
    __syncthreads();
    const float cm = fmaxf(fmaxf(redm[0][j], redm[1][j]), fmaxf(redm[2][j], redm[3][j]));
    float ssum = 0.f;
#pragma unroll
    for (int i = 0; i < 16; ++i) {
        const float e = __expf(u.Ss[seg * 16 + i][j] - cm);
        u.Ss[seg * 16 + i][j] = e;
        ssum += e;
    }
    reds[seg][j] = ssum;
    __syncthreads();
    const float inv = 1.0f / (reds[0][j] + reds[1][j] + reds[2][j] + reds[3][j]);
#pragma unroll
    for (int i = 0; i < 16; ++i)
        attn[(seg * 16 + i) * 64 + j] = u.Ss[seg * 16 + i][j] * inv;
}

// ---------------- BR ----------------
__global__ __launch_bounds__(64) void k_br(
    const float* __restrict__ bst, const float* __restrict__ bsi,
    const int* __restrict__ iti, const int* __restrict__ iii,
    const float* __restrict__ attn_t, const float* __restrict__ attn_i,
    float* __restrict__ br_t, float* __restrict__ br_i)
{
    __shared__ float bw[64];
    const int dp = blockIdx.x;
    const int h = blockIdx.y;
    const int j = threadIdx.x;
    const float* attn;
    float* out;
    if (dp < RR) {
        const int d = dp;
        const int rb = iti[d * 64];
        const float* p = bst + ((size_t)(d * 64) * 64 + j) * 4;
        bw[j] = 0.25f * (p[0] + p[1] + p[2] + p[3]);
        attn = attn_t + ((size_t)h * RR + rb) * 4096;
        out = br_t + (size_t)d * 64 * 8;
    } else {
        const int d = dp - RR;
        const int rb = iii[d];
        const float* p = bsi + ((size_t)d * 64 + j) * 4;
        bw[j] = 0.25f * (p[0] + p[1] + p[2] + p[3]);
        attn = attn_i + ((size_t)h * RR + rb) * 4096;
        out = br_i + (size_t)d * 64 * 8;
    }
    __syncthreads();
    float acc = 0.f;
#pragma unroll 8
    for (int i = 0; i < 64; ++i) acc += bw[i] * attn[i * 64 + j];
    out[(size_t)j * 8 + h] = acc;
}

// ---------------- BS raw (norms fused) ----------------
__global__ __launch_bounds__(256) void k_bs(
    const float* __restrict__ br_t, const float* __restrict__ br_i,
    float* __restrict__ raw)
{
    const int p = blockIdx.x;
#pragma unroll
    for (int it = 0; it < 16; ++it) {
        const int o = it * 256 + threadIdx.x;
        const int q = o >> 6, j = o & 63;
        const float* a = br_t + ((size_t)p * 64 + j) * 8;
        const float* b = br_i + ((size_t)q * 64 + j) * 8;
        float dot = 0.f, sa = 0.f, sb = 0.f;
#pragma unroll
        for (int h = 0; h < 8; ++h) {
            const float va = a[h], vb = b[h];
            dot += va * vb; sa += va * va; sb += vb * vb;
        }
        const float na = fmaxf(sqrtf(sa), 1e-15f);
        const float nb = fmaxf(sqrtf(sb), 1e-15f);
        raw[(size_t)p * 4096 + o] = dot / (na * nb);
    }
}

// ---------------- log-softmax rows of 27 ----------------
__global__ __launch_bounds__(256) void k_lsm(
    const float* __restrict__ cst, const float* __restrict__ csi,
    float* __restrict__ lt, float* __restrict__ li)
{
    const int row = blockIdx.x * 256 + threadIdx.x;
    if (row >= 1600 + 4096) return;
    const float* src;
    float* dst;
    if (row < 1600) {
        const int d = row >> 6, i = row & 63;
        src = cst + ((size_t)(d * 64) * 64 + i) * NCN * 4;
        dst = lt + (size_t)row * NCN;
    } else {
        const int u = row - 1600;
        const int q = u >> 6, i = u & 63;
        src = csi + ((size_t)q * 64 + i) * NCN * 4;
        dst = li + (size_t)u * NCN;
    }
    float x[NCN];
    float m = -1e30f;
#pragma unroll
    for (int k = 0; k < NCN; ++k) {
        x[k] = 0.25f * (src[k*4] + src[k*4+1] + src[k*4+2] + src[k*4+3]);
        m = fmaxf(m, x[k]);
    }
    float s = 0.f;
#pragma unroll
    for (int k = 0; k < NCN; ++k) s += __expf(x[k] - m);
    const float lse = m + __logf(s);
#pragma unroll
    for (int k = 0; k < NCN; ++k) dst[k] = x[k] - lse;
}

// ---------------- CS raw ----------------
__global__ __launch_bounds__(256) void k_cs(
    const float* __restrict__ lt, const float* __restrict__ li, float* __restrict__ raw)
{
    const int p = blockIdx.x;
    for (int it = 0; it < 16; ++it) {
        const int o = it * 256 + threadIdx.x;
        const int q = o >> 6, i = o & 63;
        const float* a = lt + ((size_t)p * 64 + i) * NCN;
        const float* b = li + ((size_t)q * 64 + i) * NCN;
        float la[NCN], lb[NCN];
        float m = -1e30f;
#pragma unroll
        for (int k = 0; k < NCN; ++k) {
            la[k] = a[k]; lb[k] = b[k];
            m = fmaxf(m, 0.5f * (la[k] + lb[k]));
        }
        float z = 0.f;
#pragma unroll
        for (int k = 0; k < NCN; ++k) z += __expf(0.5f * (la[k] + lb[k]) - m);
        const float lse = m + __logf(z);
        float kt = 0.f, ki = 0.f;
#pragma unroll
        for (int k = 0; k < NCN; ++k) {
            const float M = 0.5f * (la[k] + lb[k]) - lse;
            const float eM = __expf(M);
            kt += eM * (M - la[k]);
            ki += eM * (M - lb[k]);
        }
        raw[(size_t)p * 4096 + o] = -(kt + ki) * (0.5f / 27.0f);
    }
}

// ---------------- ob_emb = emb[gather] @ Wos^T + bos  (MFMA split) ----------------
__global__ __launch_bounds__(256) void k_obemb2(
    const float* __restrict__ emb, const float* __restrict__ Wos,
    const float* __restrict__ bos, const int* __restrict__ iii,
    const int* __restrict__ cob, float* __restrict__ ob)
{
    __shared__ __align__(16) SplitTiles sm;
    __shared__ int gidx[64];
    const int bx = blockIdx.x;
    const int tid = threadIdx.x;
    const int lane = tid & 63, w = tid >> 6;
    const int wr = w >> 1, wc = w & 1;
    const int fr = lane & 15, ch = lane >> 4;
    if (tid < 64) gidx[tid] = iii[tid] * 64 + cob[tid];
    __syncthreads();
    const float* Bbase = Wos + (size_t)bx * 64 * EE;
#define AROWP(r) (emb + (size_t)gidx[(r)] * EE)
#define BROWP(r) (Bbase + (size_t)(r) * EE)
    f32x4 acc[2][2] = {};
    for (int k0 = 0; k0 < EE; k0 += 32) {
        MFMA_STAGE_SPLIT_GEN(AROWP, BROWP, sm)
        MFMA_COMPUTE(sm)
    }
#undef AROWP
#undef BROWP
    const int rg = lane >> 4;
#pragma unroll
    for (int m = 0; m < 2; ++m)
#pragma unroll
        for (int n = 0; n < 2; ++n)
#pragma unroll
            for (int q = 0; q < 4; ++q) {
                const int row = wr * 32 + m * 16 + rg * 4 + q;
                const int col = bx * 64 + wc * 32 + n * 16 + fr;
                ob[(size_t)row * EE + col] = acc[m][n][q] + bos[col];
            }
}

// ---------------- OS raw (MFMA split) ----------------
__global__ __launch_bounds__(256) void k_os2(
    const float* __restrict__ ob, const float* __restrict__ emb, float* __restrict__ raw)
{
    __shared__ __align__(16) SplitTiles sm;
    const int p = blockIdx.x;
    const int tid = threadIdx.x;
    const int lane = tid & 63, w = tid >> 6;
    const int wr = w >> 1, wc = w & 1;
    const int fr = lane & 15, ch = lane >> 4;
    const float* Bbase = emb + (size_t)p * 64 * EE;
#define AROWP(r) (ob + (size_t)(r) * EE)
#define BROWP(r) (Bbase + (size_t)(r) * EE)
    f32x4 acc[2][2] = {};
    for (int k0 = 0; k0 < EE; k0 += 32) {
        MFMA_STAGE_SPLIT_GEN(AROWP, BROWP, sm)
        MFMA_COMPUTE(sm)
    }
#undef AROWP
#undef BROWP
    const int rg = lane >> 4;
#pragma unroll
    for (int m = 0; m < 2; ++m)
#pragma unroll
        for (int n = 0; n < 2; ++n)
#pragma unroll
            for (int q = 0; q < 4; ++q) {
                const int row = wr * 32 + m * 16 + rg * 4 + q;     // q-dim
                const int col = wc * 32 + n * 16 + fr;             // i-dim
                raw[(size_t)p * 4096 + row * 64 + col] = acc[m][n][q];
            }
}

// ---------------- final LN ----------------
__global__ __launch_bounds__(256) void k_final_ln(
    const float* __restrict__ raw,
    const float* __restrict__ BSg, const float* __restrict__ BSb,
    const float* __restrict__ CSg, const float* __restrict__ CSb,
    const float* __restrict__ OSg, const float* __restrict__ OSb,
    float* __restrict__ out)
{
    __shared__ float red[4];
    const int s = blockIdx.x, p = blockIdx.y;
    const float* g  = (s == 0) ? BSg : ((s == 1) ? CSg : OSg);
    const float* bb = (s == 0) ? BSb : ((s == 1) ? CSb : OSb);
    const float* x = raw + ((size_t)s * RR + p) * 4096;
    float v[16];
    float sum = 0.f;
#pragma unroll
    for (int it = 0; it < 16; ++it) { v[it] = x[it * 256 + threadIdx.x]; sum += v[it]; }
    sum = block_reduce_sum_256(sum, red);
    const float m = sum * (1.0f / 4096.0f);
    float sq = 0.f;
#pragma unroll
    for (int it = 0; it < 16; ++it) { const float d = v[it] - m; sq += d * d; }
    sq = block_reduce_sum_256(sq, red);
    const float rs = rsqrtf(sq * (1.0f / 4096.0f) + 1e-5f);
    float* o = out + ((size_t)s * RR + p) * 4096;
#pragma unroll
    for (int it = 0; it < 16; ++it) {
        const int oo = it * 256 + threadIdx.x;
        o[oo] = (v[it] - m) * rs * g[oo] + bb[oo];
    }
}

extern "C" void kernel_launch(void* const* d_in, const int* in_sizes, int n_in,
                              void* d_out, int out_size, void* d_ws, size_t ws_size,
                              hipStream_t stream)
{
    const float* bst = (const float*)d_in[0];
    const float* bsi = (const float*)d_in[1];
    const float* cst = (const float*)d_in[2];
    const float* csi = (const float*)d_in[3];
    const int*   iti = (const int*)d_in[4];
    const int*   iii = (const int*)d_in[5];
    const int*   cob = (const int*)d_in[6];
    const float* embw = (const float*)d_in[7];
    const float* eg  = (const float*)d_in[8];
    const float* ebb = (const float*)d_in[9];
    const float* WQt = (const float*)d_in[10];
    const float* WKt = (const float*)d_in[11];
    const float* WQi = (const float*)d_in[12];
    const float* WKi = (const float*)d_in[13];
    const float* Wos = (const float*)d_in[14];
    const float* bos = (const float*)d_in[15];
    const float* BSg = (const float*)d_in[16];
    const float* BSb = (const float*)d_in[17];
    const float* CSg = (const float*)d_in[18];
    const float* CSb = (const float*)d_in[19];
    const float* OSg = (const float*)d_in[20];
    const float* OSb = (const float*)d_in[21];

    // --- tiered workspace (floats) ---
    const size_t tailF  = 819200ull*2 + 12800 + 32768 + 43200 + 110592 + 65536 + 307200;
    const size_t baseF  = 1638400ull + 1638400;                    // emb_n + A planes
    const size_t wspF   = 33554432ull;                             // W split planes
    const size_t qk8F   = 2ull * 8 * 1600 * EE;                    // Q+K, 8 heads
    const size_t needBig = (baseF + wspF + qk8F + tailF) * 4;      // ~261 MB
    const size_t needMid = (baseF + qk8F + tailF) * 4;             // ~127 MB
    const int tier = (ws_size >= needBig) ? 2 : ((ws_size >= needMid) ? 1 : 0);

    float* ws = (float*)d_ws;
    size_t cur = 0;
    float* emb_n = ws + cur;                               cur += 1638400;
    unsigned short* Apl = (unsigned short*)(ws + cur);     cur += 1638400;
    unsigned short* wsp = nullptr;
    if (tier == 2) { wsp = (unsigned short*)(ws + cur);    cur += wspF; }
    const size_t qkSz = (tier >= 1) ? (size_t)8 * 1600 * EE : (size_t)1600 * EE;
    float* Qbuf   = ws + cur;        cur += qkSz;
    float* Kbuf   = ws + cur;        cur += qkSz;
    float* attn_t = ws + cur;        cur += 819200;
    float* attn_i = ws + cur;        cur += 819200;
    float* br_t   = ws + cur;        cur += 12800;
    float* br_i   = ws + cur;        cur += 32768;
    float* lt     = ws + cur;        cur += 43200;
    float* li     = ws + cur;        cur += 110592;
    float* ob     = ws + cur;        cur += 65536;
    float* raw    = ws + cur;        cur += 307200;

    k_ln_emb<<<1600, 256, 0, stream>>>(embw, eg, ebb, emb_n, Apl);
    if (tier == 2)
        k_splitw<<<dim3(8192, 4), 256, 0, stream>>>(WQt, WKt, WQi, WKi, wsp);

    for (int w = 0; w < 2; ++w) {
        const float* WQ = w ? WQi : WQt;
        const float* WK = w ? WKi : WKt;
        float* attn = w ? attn_i : attn_t;
        if (tier == 2) {
            k_proj2<<<1600, 256, 0, stream>>>(Apl, wsp + (size_t)(2*w) * WTEN, Qbuf, Kbuf);
            k_qk_mfma<<<dim3(25, 8), 256, 0, stream>>>(Qbuf, Kbuf, attn, 1600 * EE, RR * 4096);
        } else if (tier == 1) {
            k_proj_mfma<<<dim3(16, 25, 16), 256, 0, stream>>>(emb_n, WQ, WK, Qbuf, Kbuf, 1600 * EE);
            k_qk_mfma<<<dim3(25, 8), 256, 0, stream>>>(Qbuf, Kbuf, attn, 1600 * EE, RR * 4096);
        } else {
            for (int h = 0; h < HH; ++h) {
                k_proj_mfma<<<dim3(16, 25, 2), 256, 0, stream>>>(
                    emb_n, WQ + (size_t)h * EE * EE, WK + (size_t)h * EE * EE, Qbuf, Kbuf, 0);
                k_qk_mfma<<<dim3(25, 1), 256, 0, stream>>>(
                    Qbuf, Kbuf, attn + (size_t)h * RR * 4096, 0, 0);
            }
        }
    }

    k_br<<<dim3(RR + 64, 8), 64, 0, stream>>>(bst, bsi, iti, iii, attn_t, attn_i, br_t, br_i);
    k_bs<<<25, 256, 0, stream>>>(br_t, br_i, raw);
    k_lsm<<<23, 256, 0, stream>>>(cst, csi, lt, li);
    k_cs<<<25, 256, 0, stream>>>(lt, li, raw + 102400);
    k_obemb2<<<16, 256, 0, stream>>>(embw, Wos, bos, iii, cob, ob);
    k_os2<<<25, 256, 0, stream>>>(ob, embw, raw + 204800);
    k_final_ln<<<dim3(3, RR), 256, 0, stream>>>(raw, BSg, BSb, CSg, CSb, OSg, OSb, (float*)d_out);
}

// Round 5
// 784.091 us; speedup vs baseline: 1.2361x; 1.0994x over previous
//
#include <hip/hip_runtime.h>
#include <math.h>

#define RR 25
#define HH 8
#define EE 1024
#define NCN 27

typedef short bf16x8 __attribute__((ext_vector_type(8)));
typedef float f32x4 __attribute__((ext_vector_type(4)));
typedef unsigned short us4 __attribute__((ext_vector_type(4)));
typedef unsigned short us8 __attribute__((ext_vector_type(8)));

__device__ __forceinline__ unsigned short f2bf(float x) {
    union { float f; unsigned int u; } v; v.f = x;
    const unsigned int u = v.u;
    return (unsigned short)((u + 0x7fffu + ((u >> 16) & 1u)) >> 16);
}
__device__ __forceinline__ float bf2f(unsigned short h) {
    union { unsigned int u; float f; } v; v.u = ((unsigned int)h) << 16;
    return v.f;
}

// ---------------- block reduce (256 threads, wave=64) ----------------
__device__ __forceinline__ float block_reduce_sum_256(float v, float* red) {
#pragma unroll
    for (int off = 32; off > 0; off >>= 1) v += __shfl_down(v, off, 64);
    const int lane = threadIdx.x & 63, wid = threadIdx.x >> 6;
    if (lane == 0) red[wid] = v;
    __syncthreads();
    if (threadIdx.x == 0) red[0] = red[0] + red[1] + red[2] + red[3];
    __syncthreads();
    const float r = red[0];
    __syncthreads();
    return r;
}

// =====================================================================
// Fragment-frame layout: one 16x16x32 MFMA fragment = 1 frame = 512 shorts.
//   element (row,k): lane = (row&15) + 16*((k>>3)&3), j = k&7
//   A planes  : frame2 = ((ktile*100 + (row>>4))*2 + plane)   [M=1600]
//   W planes  : per head, frame2 = ((ktile*64 + (f>>4))*2 + plane)
// =====================================================================
#define WTEN 16777216ull
#define WHEAD 2097152ull

// ---------------- emb layernorm + frag-ordered split planes ----------------
__global__ __launch_bounds__(256) void k_ln_emb(
    const float* __restrict__ emb, const float* __restrict__ g,
    const float* __restrict__ b, float* __restrict__ out,
    unsigned short* __restrict__ Apl)
{
    __shared__ float red[4];
    const int t = blockIdx.x;
    const float* row = emb + (size_t)t * EE;
    float4 x = reinterpret_cast<const float4*>(row)[threadIdx.x];
    float s = x.x + x.y + x.z + x.w;
    s = block_reduce_sum_256(s, red);
    const float m = s * (1.0f / 1024.0f);
    const float d0 = x.x - m, d1 = x.y - m, d2 = x.z - m, d3 = x.w - m;
    float sq = d0*d0 + d1*d1 + d2*d2 + d3*d3;
    sq = block_reduce_sum_256(sq, red);
    const float rs = rsqrtf(sq * (1.0f / 1024.0f) + 1e-16f);
    const float4 gv = reinterpret_cast<const float4*>(g)[threadIdx.x];
    const float4 bv = reinterpret_cast<const float4*>(b)[threadIdx.x];
    float o[4];
    o[0] = d0 * rs * gv.x + bv.x;
    o[1] = d1 * rs * gv.y + bv.y;
    o[2] = d2 * rs * gv.z + bv.z;
    o[3] = d3 * rs * gv.w + bv.w;
    float4 of; of.x = o[0]; of.y = o[1]; of.z = o[2]; of.w = o[3];
    reinterpret_cast<float4*>(out + (size_t)t * EE)[threadIdx.x] = of;
    us4 hv, lv;
#pragma unroll
    for (int j = 0; j < 4; ++j) {
        const unsigned short h = f2bf(o[j]);
        hv[j] = h; lv[j] = f2bf(o[j] - bf2f(h));
    }
    const int k0 = threadIdx.x * 4;
    const int kt = k0 >> 5, kc = (k0 >> 3) & 3, j0 = k0 & 7;
    const int lane = (t & 15) + 16 * kc;
    const size_t base = ((size_t)(kt * 100 + (t >> 4)) * 2) * 512 + lane * 8 + j0;
    *reinterpret_cast<us4*>(Apl + base)       = hv;
    *reinterpret_cast<us4*>(Apl + base + 512) = lv;
}

// ---------------- split 4 weight tensors into frag-ordered planes ----------------
__global__ __launch_bounds__(256) void k_splitw(
    const float* __restrict__ w0, const float* __restrict__ w1,
    const float* __restrict__ w2, const float* __restrict__ w3,
    unsigned short* __restrict__ wsp)
{
    const int t = blockIdx.y;
    const float* src = (t == 0) ? w0 : ((t == 1) ? w1 : ((t == 2) ? w2 : w3));
    unsigned short* dst = wsp + (size_t)t * WTEN;
    const size_t q = (size_t)blockIdx.x * 256 + threadIdx.x;
    const float4 x = reinterpret_cast<const float4*>(src)[q];
    const float xf[4] = {x.x, x.y, x.z, x.w};
    us4 hv, lv;
#pragma unroll
    for (int j = 0; j < 4; ++j) {
        const unsigned short h = f2bf(xf[j]);
        hv[j] = h; lv[j] = f2bf(xf[j] - bf2f(h));
    }
    const size_t e4 = q * 4;
    const int h = (int)(e4 >> 20);
    const int rem = (int)(e4 & 1048575);
    const int f = rem >> 10, e = rem & 1023;
    const int kt = e >> 5, kc = (e >> 3) & 3, j0 = e & 7;
    const int lane = (f & 15) + 16 * kc;
    const size_t base = (size_t)h * WHEAD + ((size_t)(kt * 64 + (f >> 4)) * 2) * 512 + lane * 8 + j0;
    *reinterpret_cast<us4*>(dst + base)       = hv;
    *reinterpret_cast<us4*>(dst + base + 512) = lv;
}

// ---------------- fast projection v2: A via dbuf LDS, B direct to regs, prefetch ----------------
// grid x = 1600. xcd = fid&7 -> h; iw/100 -> pk; within: by fastest (B-tile L2 reuse).
__global__ __launch_bounds__(256) void k_proj2(
    const unsigned short* __restrict__ Apl,
    const unsigned short* __restrict__ Wpl,
    float* __restrict__ Qb, float* __restrict__ Kb)
{
    __shared__ __align__(16) unsigned short As_l[2][8 * 512];   // 2 x 8 KB
    const int fid = blockIdx.x;
    const int xcd = fid & 7;
    const int iw = fid >> 3;               // 0..199
    const int zsel = iw / 100;             // pk phase per XCD
    const int mb = iw % 100;
    const int bx = mb / 25;                // slow
    const int by = mb % 25;                // fast -> concurrent blocks share B-tile
    const int pk = zsel, h = xcd;
    const unsigned short* Wb = Wpl + (size_t)pk * WTEN + (size_t)h * WHEAD;
    float* C = (pk ? Kb : Qb) + (size_t)h * 1600 * EE;
    const int tid = threadIdx.x;
    const int lane = tid & 63, wv = tid >> 6;
    const int by4 = by * 4, bx16 = bx * 16;
    const int l8 = lane * 8;

    f32x4 acc[4][4] = {};
    us8 aR0[2], aR1[2];
    bf16x8 bR0[8], bR1[8];

    {   // preload kt = 0
        const unsigned short* aslab = Apl + ((size_t)by4) * 1024;
        const unsigned short* bslab = Wb + ((size_t)bx16) * 1024;
        aR0[0] = *reinterpret_cast<const us8*>(aslab + (size_t)tid * 8);
        aR0[1] = *reinterpret_cast<const us8*>(aslab + (size_t)(256 + tid) * 8);
#pragma unroll
        for (int n = 0; n < 4; ++n) {
            const int nt = wv * 4 + n;
            bR0[2*n]   = *reinterpret_cast<const bf16x8*>(bslab + (size_t)((nt*2 + 0) * 512) + l8);
            bR0[2*n+1] = *reinterpret_cast<const bf16x8*>(bslab + (size_t)((nt*2 + 1) * 512) + l8);
        }
    }

#define PROJ_PHASE(AC, BC, AN, BN, P, KT)                                        \
    {                                                                            \
        *reinterpret_cast<us8*>(&As_l[P][tid * 8]) = AC[0];                      \
        *reinterpret_cast<us8*>(&As_l[P][(256 + tid) * 8]) = AC[1];              \
        __syncthreads();                                                         \
        const int ktn = ((KT) < 31) ? (KT) + 1 : 31;                             \
        const unsigned short* aslabn = Apl + ((size_t)(ktn * 100 + by4)) * 1024; \
        const unsigned short* bslabn = Wb + ((size_t)(ktn * 64 + bx16)) * 1024;  \
        AN[0] = *reinterpret_cast<const us8*>(aslabn + (size_t)tid * 8);         \
        AN[1] = *reinterpret_cast<const us8*>(aslabn + (size_t)(256 + tid) * 8); \
        _Pragma("unroll")                                                        \
        for (int n = 0; n < 4; ++n) {                                            \
            const int nt = wv * 4 + n;                                           \
            BN[2*n]   = *reinterpret_cast<const bf16x8*>(bslabn + (size_t)((nt*2 + 0) * 512) + l8); \
            BN[2*n+1] = *reinterpret_cast<const bf16x8*>(bslabn + (size_t)((nt*2 + 1) * 512) + l8); \
        }                                                                        \
        bf16x8 ah[4], al[4];                                                     \
        _Pragma("unroll")                                                        \
        for (int m = 0; m < 4; ++m) {                                            \
            ah[m] = *reinterpret_cast<const bf16x8*>(&As_l[P][(m*2 + 0) * 512 + l8]); \
            al[m] = *reinterpret_cast<const bf16x8*>(&As_l[P][(m*2 + 1) * 512 + l8]); \
        }                                                                        \
        _Pragma("unroll")                                                        \
        for (int m = 0; m < 4; ++m)                                              \
            _Pragma("unroll")                                                    \
            for (int n = 0; n < 4; ++n) {                                        \
                acc[m][n] = __builtin_amdgcn_mfma_f32_16x16x32_bf16(ah[m], BC[2*n],   acc[m][n], 0, 0, 0); \
                acc[m][n] = __builtin_amdgcn_mfma_f32_16x16x32_bf16(ah[m], BC[2*n+1], acc[m][n], 0, 0, 0); \
                acc[m][n] = __builtin_amdgcn_mfma_f32_16x16x32_bf16(al[m], BC[2*n],   acc[m][n], 0, 0, 0); \
            }                                                                    \
    }

    for (int kt = 0; kt < 32; kt += 2) {
        PROJ_PHASE(aR0, bR0, aR1, bR1, 0, kt)
        PROJ_PHASE(aR1, bR1, aR0, bR0, 1, kt + 1)
    }
#undef PROJ_PHASE

    const int rg = lane >> 4, fr = lane & 15;
#pragma unroll
    for (int m = 0; m < 4; ++m)
#pragma unroll
        for (int n = 0; n < 4; ++n)
#pragma unroll
            for (int q = 0; q < 4; ++q) {
                const int row = by * 64 + m * 16 + rg * 4 + q;
                const int col = bx * 256 + wv * 64 + n * 16 + fr;
                C[(size_t)row * EE + col] = acc[m][n][q];
            }
}

// =====================================================================
// On-the-fly split machinery (64x64 tile, 4 waves as 2x2 quadrants)
// =====================================================================
struct SplitTiles {
    unsigned short Ah[64][40], Al[64][40], Bh[64][40], Bl[64][40];
};

#define MFMA_COMPUTE(SM)                                                         \
    {                                                                            \
        bf16x8 ah_[2], al_[2], bh_[2], bl_[2];                                   \
        _Pragma("unroll")                                                        \
        for (int m = 0; m < 2; ++m) {                                            \
            const int r = wr * 32 + m * 16 + fr;                                 \
            ah_[m] = *reinterpret_cast<const bf16x8*>(&(SM).Ah[r][ch * 8]);      \
            al_[m] = *reinterpret_cast<const bf16x8*>(&(SM).Al[r][ch * 8]);      \
        }                                                                        \
        _Pragma("unroll")                                                        \
        for (int n = 0; n < 2; ++n) {                                            \
            const int r = wc * 32 + n * 16 + fr;                                 \
            bh_[n] = *reinterpret_cast<const bf16x8*>(&(SM).Bh[r][ch * 8]);      \
            bl_[n] = *reinterpret_cast<const bf16x8*>(&(SM).Bl[r][ch * 8]);      \
        }                                                                        \
        _Pragma("unroll")                                                        \
        for (int m = 0; m < 2; ++m)                                              \
            _Pragma("unroll")                                                    \
            for (int n = 0; n < 2; ++n) {                                        \
                acc[m][n] = __builtin_amdgcn_mfma_f32_16x16x32_bf16(ah_[m], bh_[n], acc[m][n], 0, 0, 0); \
                acc[m][n] = __builtin_amdgcn_mfma_f32_16x16x32_bf16(ah_[m], bl_[n], acc[m][n], 0, 0, 0); \
                acc[m][n] = __builtin_amdgcn_mfma_f32_16x16x32_bf16(al_[m], bh_[n], acc[m][n], 0, 0, 0); \
            }                                                                    \
    }

#define MFMA_STAGE_SPLIT_GEN(AROW, BROW, SM)                                     \
    {                                                                            \
        float4 ra[2], rb[2];                                                     \
        _Pragma("unroll")                                                        \
        for (int l = 0; l < 2; ++l) {                                            \
            const int id = l * 256 + tid;                                        \
            const int row = id >> 3, c4 = (id & 7) * 4;                          \
            ra[l] = *reinterpret_cast<const float4*>((AROW(row)) + k0 + c4);     \
            rb[l] = *reinterpret_cast<const float4*>((BROW(row)) + k0 + c4);     \
        }                                                                        \
        __syncthreads();                                                         \
        _Pragma("unroll")                                                        \
        for (int l = 0; l < 2; ++l) {                                            \
            const int id = l * 256 + tid;                                        \
            const int row = id >> 3, c4 = (id & 7) * 4;                          \
            const float xa[4] = {ra[l].x, ra[l].y, ra[l].z, ra[l].w};            \
            const float xb[4] = {rb[l].x, rb[l].y, rb[l].z, rb[l].w};            \
            us4 ahv, alv, bhv, blv;                                              \
            _Pragma("unroll")                                                    \
            for (int j = 0; j < 4; ++j) {                                        \
                const unsigned short ha = f2bf(xa[j]);                           \
                ahv[j] = ha; alv[j] = f2bf(xa[j] - bf2f(ha));                    \
                const unsigned short hb = f2bf(xb[j]);                           \
                bhv[j] = hb; blv[j] = f2bf(xb[j] - bf2f(hb));                    \
            }                                                                    \
            *reinterpret_cast<us4*>(&(SM).Ah[row][c4]) = ahv;                    \
            *reinterpret_cast<us4*>(&(SM).Al[row][c4]) = alv;                    \
            *reinterpret_cast<us4*>(&(SM).Bh[row][c4]) = bhv;                    \
            *reinterpret_cast<us4*>(&(SM).Bl[row][c4]) = blv;                    \
        }                                                                        \
        __syncthreads();                                                         \
    }

// ---------------- fallback projection (on-the-fly split, f32 inputs) ----------------
__global__ __launch_bounds__(256) void k_proj_mfma(
    const float* __restrict__ A,
    const float* __restrict__ WQ, const float* __restrict__ WK,
    float* __restrict__ Qb, float* __restrict__ Kb, int qkHeadStride)
{
    __shared__ __align__(16) SplitTiles sm;
    const int h = blockIdx.z >> 1;
    const int pk = blockIdx.z & 1;
    const float* W = (pk ? WK : WQ) + (size_t)h * EE * EE;
    float* C = (pk ? Kb : Qb) + (size_t)h * qkHeadStride;
    const int bx = blockIdx.x, by = blockIdx.y;
    const int tid = threadIdx.x;
    const int lane = tid & 63, w = tid >> 6;
    const int wr = w >> 1, wc = w & 1;
    const int fr = lane & 15, ch = lane >> 4;
    const float* Abase = A + (size_t)by * 64 * EE;
    const float* Bbase = W + (size_t)bx * 64 * EE;
#define AROWP(r) (Abase + (size_t)(r) * EE)
#define BROWP(r) (Bbase + (size_t)(r) * EE)
    f32x4 acc[2][2] = {};
    for (int k0 = 0; k0 < EE; k0 += 32) {
        MFMA_STAGE_SPLIT_GEN(AROWP, BROWP, sm)
        MFMA_COMPUTE(sm)
    }
#undef AROWP
#undef BROWP
    const int rg = lane >> 4;
#pragma unroll
    for (int m = 0; m < 2; ++m)
#pragma unroll
        for (int n = 0; n < 2; ++n)
#pragma unroll
            for (int q = 0; q < 4; ++q) {
                const int row = by * 64 + wr * 32 + m * 16 + rg * 4 + q;
                const int col = bx * 64 + wc * 32 + n * 16 + fr;
                C[(size_t)row * EE + col] = acc[m][n][q];
            }
}

// ---------------- QK^T (/32) + column softmax ----------------
__global__ __launch_bounds__(256) void k_qk_mfma(
    const float* __restrict__ Qall, const float* __restrict__ Kall,
    float* __restrict__ attn_all, int qkHeadStride, int attnHeadStride)
{
    __shared__ __align__(16) union { SplitTiles t; float Ss[64][65]; } u;
    __shared__ float redm[4][64];
    __shared__ float reds[4][64];
    const int r = blockIdx.x;
    const int h = blockIdx.y;
    const float* Q = Qall + (size_t)h * qkHeadStride;
    const float* K = Kall + (size_t)h * qkHeadStride;
    float* attn = attn_all + (size_t)h * attnHeadStride + (size_t)r * 4096;
    const int tid = threadIdx.x;
    const int lane = tid & 63, w = tid >> 6;
    const int wr = w >> 1, wc = w & 1;
    const int fr = lane & 15, ch = lane >> 4;
    const float* Abase = Q + (size_t)r * 64 * EE;
    const float* Bbase = K + (size_t)r * 64 * EE;
#define AROWP(rr) (Abase + (size_t)(rr) * EE)
#define BROWP(rr) (Bbase + (size_t)(rr) * EE)
    f32x4 acc[2][2] = {};
    for (int k0 = 0; k0 < EE; k0 += 32) {
        MFMA_STAGE_SPLIT_GEN(AROWP, BROWP, u.t)
        MFMA_COMPUTE(u.t)
    }
#undef AROWP
#undef BROWP
    __syncthreads();
    const int rg = lane >> 4;
#pragma unroll
    for (int m = 0; m < 2; ++m)
#pragma unroll
        for (int n = 0; n < 2; ++n)
#pragma unroll
            for (int q = 0; q < 4; ++q)
                u.Ss[wr * 32 + m * 16 + rg * 4 + q][wc * 32 + n * 16 + fr] =
                    acc[m][n][q] * (1.0f / 32.0f);
    __syncthreads();
    const int j = tid & 63, seg = tid >> 6;
    float mx = -1e30f;
#pragma unroll
    for (int i = 0; i < 16; ++i) mx = fmaxf(mx, u.Ss[seg * 16 + i][j]);
    redm[seg][j] = mx;
    __syncthreads();
    const float cm = fmaxf(fmaxf(redm[0][j], redm[1][j]), fmaxf(redm[2][j], redm[3][j]));
    float ssum = 0.f;
#pragma unroll
    for (int i = 0; i < 16; ++i) {
        const float e = __expf(u.Ss[seg * 16 + i][j] - cm);
        u.Ss[seg * 16 + i][j] = e;
        ssum += e;
    }
    reds[seg][j] = ssum;
    __syncthreads();
    const float inv = 1.0f / (reds[0][j] + reds[1][j] + reds[2][j] + reds[3][j]);
#pragma unroll
    for (int i = 0; i < 16; ++i)
        attn[(seg * 16 + i) * 64 + j] = u.Ss[seg * 16 + i][j] * inv;
}

// ---------------- BR ----------------
__global__ __launch_bounds__(64) void k_br(
    const float* __restrict__ bst, const float* __restrict__ bsi,
    const int* __restrict__ iti, const int* __restrict__ iii,
    const float* __restrict__ attn_t, const float* __restrict__ attn_i,
    float* __restrict__ br_t, float* __restrict__ br_i)
{
    __shared__ float bw[64];
    const int dp = blockIdx.x;
    const int h = blockIdx.y;
    const int j = threadIdx.x;
    const float* attn;
    float* out;
    if (dp < RR) {
        const int d = dp;
        const int rb = iti[d * 64];
        const float* p = bst + ((size_t)(d * 64) * 64 + j) * 4;
        bw[j] = 0.25f * (p[0] + p[1] + p[2] + p[3]);
        attn = attn_t + ((size_t)h * RR + rb) * 4096;
        out = br_t + (size_t)d * 64 * 8;
    } else {
        const int d = dp - RR;
        const int rb = iii[d];
        const float* p = bsi + ((size_t)d * 64 + j) * 4;
        bw[j] = 0.25f * (p[0] + p[1] + p[2] + p[3]);
        attn = attn_i + ((size_t)h * RR + rb) * 4096;
        out = br_i + (size_t)d * 64 * 8;
    }
    __syncthreads();
    float acc = 0.f;
#pragma unroll 8
    for (int i = 0; i < 64; ++i) acc += bw[i] * attn[i * 64 + j];
    out[(size_t)j * 8 + h] = acc;
}

// ---------------- BS raw (norms fused) ----------------
__global__ __launch_bounds__(256) void k_bs(
    const float* __restrict__ br_t, const float* __restrict__ br_i,
    float* __restrict__ raw)
{
    const int p = blockIdx.x;
#pragma unroll
    for (int it = 0; it < 16; ++it) {
        const int o = it * 256 + threadIdx.x;
        const int q = o >> 6, j = o & 63;
        const float* a = br_t + ((size_t)p * 64 + j) * 8;
        const float* b = br_i + ((size_t)q * 64 + j) * 8;
        float dot = 0.f, sa = 0.f, sb = 0.f;
#pragma unroll
        for (int h = 0; h < 8; ++h) {
            const float va = a[h], vb = b[h];
            dot += va * vb; sa += va * va; sb += vb * vb;
        }
        const float na = fmaxf(sqrtf(sa), 1e-15f);
        const float nb = fmaxf(sqrtf(sb), 1e-15f);
        raw[(size_t)p * 4096 + o] = dot / (na * nb);
    }
}

// ---------------- log-softmax rows of 27 ----------------
__global__ __launch_bounds__(256) void k_lsm(
    const float* __restrict__ cst, const float* __restrict__ csi,
    float* __restrict__ lt, float* __restrict__ li)
{
    const int row = blockIdx.x * 256 + threadIdx.x;
    if (row >= 1600 + 4096) return;
    const float* src;
    float* dst;
    if (row < 1600) {
        const int d = row >> 6, i = row & 63;
        src = cst + ((size_t)(d * 64) * 64 + i) * NCN * 4;
        dst = lt + (size_t)row * NCN;
    } else {
        const int u = row - 1600;
        const int q = u >> 6, i = u & 63;
        src = csi + ((size_t)q * 64 + i) * NCN * 4;
        dst = li + (size_t)u * NCN;
    }
    float x[NCN];
    float m = -1e30f;
#pragma unroll
    for (int k = 0; k < NCN; ++k) {
        x[k] = 0.25f * (src[k*4] + src[k*4+1] + src[k*4+2] + src[k*4+3]);
        m = fmaxf(m, x[k]);
    }
    float s = 0.f;
#pragma unroll
    for (int k = 0; k < NCN; ++k) s += __expf(x[k] - m);
    const float lse = m + __logf(s);
#pragma unroll
    for (int k = 0; k < NCN; ++k) dst[k] = x[k] - lse;
}

// ---------------- CS raw ----------------
__global__ __launch_bounds__(256) void k_cs(
    const float* __restrict__ lt, const float* __restrict__ li, float* __restrict__ raw)
{
    const int p = blockIdx.x;
    for (int it = 0; it < 16; ++it) {
        const int o = it * 256 + threadIdx.x;
        const int q = o >> 6, i = o & 63;
        const float* a = lt + ((size_t)p * 64 + i) * NCN;
        const float* b = li + ((size_t)q * 64 + i) * NCN;
        float la[NCN], lb[NCN];
        float m = -1e30f;
#pragma unroll
        for (int k = 0; k < NCN; ++k) {
            la[k] = a[k]; lb[k] = b[k];
            m = fmaxf(m, 0.5f * (la[k] + lb[k]));
        }
        float z = 0.f;
#pragma unroll
        for (int k = 0; k < NCN; ++k) z += __expf(0.5f * (la[k] + lb[k]) - m);
        const float lse = m + __logf(z);
        float kt = 0.f, ki = 0.f;
#pragma unroll
        for (int k = 0; k < NCN; ++k) {
            const float M = 0.5f * (la[k] + lb[k]) - lse;
            const float eM = __expf(M);
            kt += eM * (M - la[k]);
            ki += eM * (M - lb[k]);
        }
        raw[(size_t)p * 4096 + o] = -(kt + ki) * (0.5f / 27.0f);
    }
}

// ---------------- ob_emb = emb[gather] @ Wos^T + bos  (MFMA split) ----------------
__global__ __launch_bounds__(256) void k_obemb2(
    const float* __restrict__ emb, const float* __restrict__ Wos,
    const float* __restrict__ bos, const int* __restrict__ iii,
    const int* __restrict__ cob, float* __restrict__ ob)
{
    __shared__ __align__(16) SplitTiles sm;
    __shared__ int gidx[64];
    const int bx = blockIdx.x;
    const int tid = threadIdx.x;
    const int lane = tid & 63, w = tid >> 6;
    const int wr = w >> 1, wc = w & 1;
    const int fr = lane & 15, ch = lane >> 4;
    if (tid < 64) gidx[tid] = iii[tid] * 64 + cob[tid];
    __syncthreads();
    const float* Bbase = Wos + (size_t)bx * 64 * EE;
#define AROWP(r) (emb + (size_t)gidx[(r)] * EE)
#define BROWP(r) (Bbase + (size_t)(r) * EE)
    f32x4 acc[2][2] = {};
    for (int k0 = 0; k0 < EE; k0 += 32) {
        MFMA_STAGE_SPLIT_GEN(AROWP, BROWP, sm)
        MFMA_COMPUTE(sm)
    }
#undef AROWP
#undef BROWP
    const int rg = lane >> 4;
#pragma unroll
    for (int m = 0; m < 2; ++m)
#pragma unroll
        for (int n = 0; n < 2; ++n)
#pragma unroll
            for (int q = 0; q < 4; ++q) {
                const int row = wr * 32 + m * 16 + rg * 4 + q;
                const int col = bx * 64 + wc * 32 + n * 16 + fr;
                ob[(size_t)row * EE + col] = acc[m][n][q] + bos[col];
            }
}

// ---------------- OS raw (MFMA split) ----------------
__global__ __launch_bounds__(256) void k_os2(
    const float* __restrict__ ob, const float* __restrict__ emb, float* __restrict__ raw)
{
    __shared__ __align__(16) SplitTiles sm;
    const int p = blockIdx.x;
    const int tid = threadIdx.x;
    const int lane = tid & 63, w = tid >> 6;
    const int wr = w >> 1, wc = w & 1;
    const int fr = lane & 15, ch = lane >> 4;
    const float* Bbase = emb + (size_t)p * 64 * EE;
#define AROWP(r) (ob + (size_t)(r) * EE)
#define BROWP(r) (Bbase + (size_t)(r) * EE)
    f32x4 acc[2][2] = {};
    for (int k0 = 0; k0 < EE; k0 += 32) {
        MFMA_STAGE_SPLIT_GEN(AROWP, BROWP, sm)
        MFMA_COMPUTE(sm)
    }
#undef AROWP
#undef BROWP
    const int rg = lane >> 4;
#pragma unroll
    for (int m = 0; m < 2; ++m)
#pragma unroll
        for (int n = 0; n < 2; ++n)
#pragma unroll
            for (int q = 0; q < 4; ++q) {
                const int row = wr * 32 + m * 16 + rg * 4 + q;
                const int col = wc * 32 + n * 16 + fr;
                raw[(size_t)p * 4096 + row * 64 + col] = acc[m][n][q];
            }
}

// ---------------- final LN ----------------
__global__ __launch_bounds__(256) void k_final_ln(
    const float* __restrict__ raw,
    const float* __restrict__ BSg, const float* __restrict__ BSb,
    const float* __restrict__ CSg, const float* __restrict__ CSb,
    const float* __restrict__ OSg, const float* __restrict__ OSb,
    float* __restrict__ out)
{
    __shared__ float red[4];
    const int s = blockIdx.x, p = blockIdx.y;
    const float* g  = (s == 0) ? BSg : ((s == 1) ? CSg : OSg);
    const float* bb = (s == 0) ? BSb : ((s == 1) ? CSb : OSb);
    const float* x = raw + ((size_t)s * RR + p) * 4096;
    float v[16];
    float sum = 0.f;
#pragma unroll
    for (int it = 0; it < 16; ++it) { v[it] = x[it * 256 + threadIdx.x]; sum += v[it]; }
    sum = block_reduce_sum_256(sum, red);
    const float m = sum * (1.0f / 4096.0f);
    float sq = 0.f;
#pragma unroll
    for (int it = 0; it < 16; ++it) { const float d = v[it] - m; sq += d * d; }
    sq = block_reduce_sum_256(sq, red);
    const float rs = rsqrtf(sq * (1.0f / 4096.0f) + 1e-5f);
    float* o = out + ((size_t)s * RR + p) * 4096;
#pragma unroll
    for (int it = 0; it < 16; ++it) {
        const int oo = it * 256 + threadIdx.x;
        o[oo] = (v[it] - m) * rs * g[oo] + bb[oo];
    }
}

extern "C" void kernel_launch(void* const* d_in, const int* in_sizes, int n_in,
                              void* d_out, int out_size, void* d_ws, size_t ws_size,
                              hipStream_t stream)
{
    const float* bst = (const float*)d_in[0];
    const float* bsi = (const float*)d_in[1];
    const float* cst = (const float*)d_in[2];
    const float* csi = (const float*)d_in[3];
    const int*   iti = (const int*)d_in[4];
    const int*   iii = (const int*)d_in[5];
    const int*   cob = (const int*)d_in[6];
    const float* embw = (const float*)d_in[7];
    const float* eg  = (const float*)d_in[8];
    const float* ebb = (const float*)d_in[9];
    const float* WQt = (const float*)d_in[10];
    const float* WKt = (const float*)d_in[11];
    const float* WQi = (const float*)d_in[12];
    const float* WKi = (const float*)d_in[13];
    const float* Wos = (const float*)d_in[14];
    const float* bos = (const float*)d_in[15];
    const float* BSg = (const float*)d_in[16];
    const float* BSb = (const float*)d_in[17];
    const float* CSg = (const float*)d_in[18];
    const float* CSb = (const float*)d_in[19];
    const float* OSg = (const float*)d_in[20];
    const float* OSb = (const float*)d_in[21];

    // --- tiered workspace (floats) ---
    const size_t tailF  = 819200ull*2 + 12800 + 32768 + 43200 + 110592 + 65536 + 307200;
    const size_t baseF  = 1638400ull + 1638400;                    // emb_n + A planes
    const size_t wspF   = 33554432ull;                             // W split planes
    const size_t qk8F   = 2ull * 8 * 1600 * EE;                    // Q+K, 8 heads
    const size_t needBig = (baseF + wspF + qk8F + tailF) * 4;      // ~261 MB
    const size_t needMid = (baseF + qk8F + tailF) * 4;             // ~127 MB
    const int tier = (ws_size >= needBig) ? 2 : ((ws_size >= needMid) ? 1 : 0);

    float* ws = (float*)d_ws;
    size_t cur = 0;
    float* emb_n = ws + cur;                               cur += 1638400;
    unsigned short* Apl = (unsigned short*)(ws + cur);     cur += 1638400;
    unsigned short* wsp = nullptr;
    if (tier == 2) { wsp = (unsigned short*)(ws + cur);    cur += wspF; }
    const size_t qkSz = (tier >= 1) ? (size_t)8 * 1600 * EE : (size_t)1600 * EE;
    float* Qbuf   = ws + cur;        cur += qkSz;
    float* Kbuf   = ws + cur;        cur += qkSz;
    float* attn_t = ws + cur;        cur += 819200;
    float* attn_i = ws + cur;        cur += 819200;
    float* br_t   = ws + cur;        cur += 12800;
    float* br_i   = ws + cur;        cur += 32768;
    float* lt     = ws + cur;        cur += 43200;
    float* li     = ws + cur;        cur += 110592;
    float* ob     = ws + cur;        cur += 65536;
    float* raw    = ws + cur;        cur += 307200;

    k_ln_emb<<<1600, 256, 0, stream>>>(embw, eg, ebb, emb_n, Apl);
    if (tier == 2)
        k_splitw<<<dim3(8192, 4), 256, 0, stream>>>(WQt, WKt, WQi, WKi, wsp);

    for (int w = 0; w < 2; ++w) {
        const float* WQ = w ? WQi : WQt;
        const float* WK = w ? WKi : WKt;
        float* attn = w ? attn_i : attn_t;
        if (tier == 2) {
            k_proj2<<<1600, 256, 0, stream>>>(Apl, wsp + (size_t)(2*w) * WTEN, Qbuf, Kbuf);
            k_qk_mfma<<<dim3(25, 8), 256, 0, stream>>>(Qbuf, Kbuf, attn, 1600 * EE, RR * 4096);
        } else if (tier == 1) {
            k_proj_mfma<<<dim3(16, 25, 16), 256, 0, stream>>>(emb_n, WQ, WK, Qbuf, Kbuf, 1600 * EE);
            k_qk_mfma<<<dim3(25, 8), 256, 0, stream>>>(Qbuf, Kbuf, attn, 1600 * EE, RR * 4096);
        } else {
            for (int h = 0; h < HH; ++h) {
                k_proj_mfma<<<dim3(16, 25, 2), 256, 0, stream>>>(
                    emb_n, WQ + (size_t)h * EE * EE, WK + (size_t)h * EE * EE, Qbuf, Kbuf, 0);
                k_qk_mfma<<<dim3(25, 1), 256, 0, stream>>>(
                    Qbuf, Kbuf, attn + (size_t)h * RR * 4096, 0, 0);
            }
        }
    }

    k_br<<<dim3(RR + 64, 8), 64, 0, stream>>>(bst, bsi, iti, iii, attn_t, attn_i, br_t, br_i);
    k_bs<<<25, 256, 0, stream>>>(br_t, br_i, raw);
    k_lsm<<<23, 256, 0, stream>>>(cst, csi, lt, li);
    k_cs<<<25, 256, 0, stream>>>(lt, li, raw + 102400);
    k_obemb2<<<16, 256, 0, stream>>>(embw, Wos, bos, iii, cob, ob);
    k_os2<<<25, 256, 0, stream>>>(ob, embw, raw + 204800);
    k_final_ln<<<dim3(3, RR), 256, 0, stream>>>(raw, BSg, BSb, CSg, CSb, OSg, OSb, (float*)d_out);
}